// Round 3
// baseline (102.578 us; speedup 1.0000x reference)
//
#include <hip/hip_runtime.h>
#include <math.h>

// Problem constants
#define NB 256   // batches
#define NN 32    // agents
#define DD 128   // state dim
#define NA 16    // action dim
#define HH 256   // hidden

static __device__ __forceinline__ float4 ld4(const float* p){ return *reinterpret_cast<const float4*>(p); }
static __device__ __forceinline__ void st4f(float* p, float4 v){ *reinterpret_cast<float4*>(p) = v; }

static __device__ __forceinline__ unsigned f2bf(float x){
    unsigned u = __float_as_uint(x);
    u += 0x7fffu + ((u >> 16) & 1u);   // round-to-nearest-even
    return u >> 16;
}
static __device__ __forceinline__ unsigned pack2(float a, float b){
    return f2bf(a) | (f2bf(b) << 16);
}

static __device__ __forceinline__ void zero4(float acc[4][4]){
    #pragma unroll
    for (int u=0;u<4;u++){
        #pragma unroll
        for (int c=0;c<4;c++) acc[u][c]=0.f;
    }
}
static __device__ __forceinline__ void zero2(float acc[2][4]){
    #pragma unroll
    for (int u=0;u<2;u++){
        #pragma unroll
        for (int c=0;c<4;c++) acc[u][c]=0.f;
    }
}

// ===================== 256-thread pre-kernel GEMM =====================
// Y[32][*] tile: rows q+8u (q=t>>5), cols c0..c0+3 (c0=(t&31)*4)
template<int K>
static __device__ __forceinline__ void gemm_acc(const float* __restrict__ X, int ldx,
                                                const float* __restrict__ W, int ldw,
                                                float acc[4][4], int q, int c0)
{
    #pragma unroll 2
    for (int k = 0; k < K; k += 4) {
        float4 xv[4];
        #pragma unroll
        for (int u = 0; u < 4; u++) xv[u] = ld4(X + (q + 8*u)*ldx + k);
        #pragma unroll
        for (int kk = 0; kk < 4; kk++) {
            float4 wv = ld4(W + (k + kk)*ldw + c0);
            #pragma unroll
            for (int u = 0; u < 4; u++) {
                float x = (kk==0) ? xv[u].x : (kk==1) ? xv[u].y : (kk==2) ? xv[u].z : xv[u].w;
                acc[u][0] = fmaf(x, wv.x, acc[u][0]);
                acc[u][1] = fmaf(x, wv.y, acc[u][1]);
                acc[u][2] = fmaf(x, wv.z, acc[u][2]);
                acc[u][3] = fmaf(x, wv.w, acc[u][3]);
            }
        }
    }
}

// WavW1 = Wav @ W1  [128][256], 8 blocks (4 row-tiles x 2 col-halves)
__global__ __launch_bounds__(256)
void k_pre1(const float* __restrict__ Wav, const float* __restrict__ W1,
            float* __restrict__ WavW1)
{
    __shared__ float X[32*132];
    const int t = threadIdx.x;
    const int rt = blockIdx.x >> 1, ch = blockIdx.x & 1;
    const float* src = Wav + rt*32*128;
    #pragma unroll
    for (int u=0;u<4;u++){ int i4 = t + 256*u; st4f(X + (i4>>5)*132 + (i4&31)*4, ld4(src + i4*4)); }
    __syncthreads();
    const int q = t>>5, c0 = (t&31)*4;
    float acc[4][4]; zero4(acc);
    gemm_acc<128>(X, 132, W1 + ch*128, 256, acc, q, c0);
    #pragma unroll
    for (int u=0;u<4;u++)
        st4f(WavW1 + (rt*32 + q + 8*u)*256 + ch*128 + c0,
             make_float4(acc[u][0],acc[u][1],acc[u][2],acc[u][3]));
}

// WA = We[:128] @ WavW1 [128][256] (blocks 0..7); WB = We[128:] @ WavW1 [16][256] (block 8)
__global__ __launch_bounds__(256)
void k_pre2(const float* __restrict__ We, const float* __restrict__ WavW1,
            float* __restrict__ WA, float* __restrict__ WB)
{
    __shared__ float X[32*132];
    const int t = threadIdx.x;
    const int bb = blockIdx.x;
    if (bb < 8) {
        const int rt = bb >> 1, ch = bb & 1;
        const float* src = We + rt*32*128;
        #pragma unroll
        for (int u=0;u<4;u++){ int i4 = t + 256*u; st4f(X + (i4>>5)*132 + (i4&31)*4, ld4(src + i4*4)); }
        __syncthreads();
        const int q = t>>5, c0 = (t&31)*4;
        float acc[4][4]; zero4(acc);
        gemm_acc<128>(X, 132, WavW1 + ch*128, 256, acc, q, c0);
        #pragma unroll
        for (int u=0;u<4;u++)
            st4f(WA + (rt*32 + q + 8*u)*256 + ch*128 + c0,
                 make_float4(acc[u][0],acc[u][1],acc[u][2],acc[u][3]));
    } else {
        const float* src = We + 128*128;   // 16x128
        #pragma unroll
        for (int u=0;u<2;u++){ int i4 = t + 256*u; st4f(X + (i4>>5)*132 + (i4&31)*4, ld4(src + i4*4)); }
        __syncthreads();
        const int q2 = t>>6, c6 = (t&63)*4;
        float acc[4][4]; zero4(acc);
        #pragma unroll 2
        for (int k=0;k<128;k+=4){
            float4 xv[4];
            #pragma unroll
            for (int u=0;u<4;u++) xv[u] = ld4(X + (q2 + 4*u)*132 + k);
            #pragma unroll
            for (int kk=0;kk<4;kk++){
                float4 wv = ld4(WavW1 + (k+kk)*256 + c6);
                #pragma unroll
                for (int u=0;u<4;u++){
                    float e = (kk==0)?xv[u].x:(kk==1)?xv[u].y:(kk==2)?xv[u].z:xv[u].w;
                    acc[u][0]=fmaf(e,wv.x,acc[u][0]); acc[u][1]=fmaf(e,wv.y,acc[u][1]);
                    acc[u][2]=fmaf(e,wv.z,acc[u][2]); acc[u][3]=fmaf(e,wv.w,acc[u][3]);
                }
            }
        }
        #pragma unroll
        for (int u=0;u<4;u++)
            st4f(WB + (q2 + 4*u)*256 + c6, make_float4(acc[u][0],acc[u][1],acc[u][2],acc[u][3]));
    }
}

// ===================== 512-thread main-kernel GEMM helpers =====================
// 32x128 out: rows rg, rg+16 (rg=t>>5 in 0..15), cols c0..c0+3 (c0=(t&31)*4)
template<int K>
static __device__ __forceinline__ void gemm2(const float* __restrict__ X, int ldx,
                                             const float* __restrict__ W, int ldw,
                                             float acc[2][4], int rg, int c0)
{
    #pragma unroll 2
    for (int k = 0; k < K; k += 4) {
        float4 x0 = ld4(X + rg*ldx + k);
        float4 x1 = ld4(X + (rg+16)*ldx + k);
        #pragma unroll
        for (int kk = 0; kk < 4; kk++) {
            float4 wv = ld4(W + (k+kk)*ldw + c0);
            float e0 = (kk==0)?x0.x:(kk==1)?x0.y:(kk==2)?x0.z:x0.w;
            float e1 = (kk==0)?x1.x:(kk==1)?x1.y:(kk==2)?x1.z:x1.w;
            acc[0][0]=fmaf(e0,wv.x,acc[0][0]); acc[0][1]=fmaf(e0,wv.y,acc[0][1]);
            acc[0][2]=fmaf(e0,wv.z,acc[0][2]); acc[0][3]=fmaf(e0,wv.w,acc[0][3]);
            acc[1][0]=fmaf(e1,wv.x,acc[1][0]); acc[1][1]=fmaf(e1,wv.y,acc[1][1]);
            acc[1][2]=fmaf(e1,wv.z,acc[1][2]); acc[1][3]=fmaf(e1,wv.w,acc[1][3]);
        }
    }
}

// same, but two W streams sharing the X reads
template<int K>
static __device__ __forceinline__ void gemm2_dual(const float* __restrict__ X, int ldx,
                                                  const float* __restrict__ Wa,
                                                  const float* __restrict__ Wb, int ldw,
                                                  float a[2][4], float b[2][4], int rg, int c0)
{
    #pragma unroll 2
    for (int k = 0; k < K; k += 4) {
        float4 x0 = ld4(X + rg*ldx + k);
        float4 x1 = ld4(X + (rg+16)*ldx + k);
        #pragma unroll
        for (int kk = 0; kk < 4; kk++) {
            float4 wa = ld4(Wa + (k+kk)*ldw + c0);
            float4 wb = ld4(Wb + (k+kk)*ldw + c0);
            float e0 = (kk==0)?x0.x:(kk==1)?x0.y:(kk==2)?x0.z:x0.w;
            float e1 = (kk==0)?x1.x:(kk==1)?x1.y:(kk==2)?x1.z:x1.w;
            a[0][0]=fmaf(e0,wa.x,a[0][0]); a[0][1]=fmaf(e0,wa.y,a[0][1]);
            a[0][2]=fmaf(e0,wa.z,a[0][2]); a[0][3]=fmaf(e0,wa.w,a[0][3]);
            a[1][0]=fmaf(e1,wa.x,a[1][0]); a[1][1]=fmaf(e1,wa.y,a[1][1]);
            a[1][2]=fmaf(e1,wa.z,a[1][2]); a[1][3]=fmaf(e1,wa.w,a[1][3]);
            b[0][0]=fmaf(e0,wb.x,b[0][0]); b[0][1]=fmaf(e0,wb.y,b[0][1]);
            b[0][2]=fmaf(e0,wb.z,b[0][2]); b[0][3]=fmaf(e0,wb.w,b[0][3]);
            b[1][0]=fmaf(e1,wb.x,b[1][0]); b[1][1]=fmaf(e1,wb.y,b[1][1]);
            b[1][2]=fmaf(e1,wb.z,b[1][2]); b[1][3]=fmaf(e1,wb.w,b[1][3]);
        }
    }
}

// 32x256 out: rows r8+8u (r8=t>>6 in 0..7), cols c6..c6+3 (c6=(t&63)*4). Accumulates.
template<int K>
static __device__ __forceinline__ void gemm4(const float* __restrict__ X, int ldx,
                                             const float* __restrict__ W, int ldw,
                                             float acc[4][4], int r8, int c6)
{
    #pragma unroll 2
    for (int k = 0; k < K; k += 4) {
        float4 xv[4];
        #pragma unroll
        for (int u=0;u<4;u++) xv[u] = ld4(X + (r8 + 8*u)*ldx + k);
        #pragma unroll
        for (int kk=0;kk<4;kk++){
            float4 wv = ld4(W + (k+kk)*ldw + c6);
            #pragma unroll
            for (int u=0;u<4;u++){
                float e = (kk==0)?xv[u].x:(kk==1)?xv[u].y:(kk==2)?xv[u].z:xv[u].w;
                acc[u][0]=fmaf(e,wv.x,acc[u][0]); acc[u][1]=fmaf(e,wv.y,acc[u][1]);
                acc[u][2]=fmaf(e,wv.z,acc[u][2]); acc[u][3]=fmaf(e,wv.w,acc[u][3]);
            }
        }
    }
}

// gemm4 with X = (Xa - Xb) computed on the fly
template<int K>
static __device__ __forceinline__ void gemm4_diff(const float* __restrict__ Xa,
                                                  const float* __restrict__ Xb, int ldx,
                                                  const float* __restrict__ W, int ldw,
                                                  float acc[4][4], int r8, int c6)
{
    #pragma unroll
    for (int k = 0; k < K; k += 4) {
        float4 xv[4];
        #pragma unroll
        for (int u=0;u<4;u++){
            float4 a = ld4(Xa + (r8 + 8*u)*ldx + k);
            float4 b = ld4(Xb + (r8 + 8*u)*ldx + k);
            xv[u] = make_float4(a.x-b.x, a.y-b.y, a.z-b.z, a.w-b.w);
        }
        #pragma unroll
        for (int kk=0;kk<4;kk++){
            float4 wv = ld4(W + (k+kk)*ldw + c6);
            #pragma unroll
            for (int u=0;u<4;u++){
                float e = (kk==0)?xv[u].x:(kk==1)?xv[u].y:(kk==2)?xv[u].z:xv[u].w;
                acc[u][0]=fmaf(e,wv.x,acc[u][0]); acc[u][1]=fmaf(e,wv.y,acc[u][1]);
                acc[u][2]=fmaf(e,wv.z,acc[u][2]); acc[u][3]=fmaf(e,wv.w,acc[u][3]);
            }
        }
    }
}

static __device__ __forceinline__ void store2(float* __restrict__ Y, float acc[2][4], int rg, int c0){
    st4f(Y + rg*132 + c0,      make_float4(acc[0][0],acc[0][1],acc[0][2],acc[0][3]));
    st4f(Y + (rg+16)*132 + c0, make_float4(acc[1][0],acc[1][1],acc[1][2],acc[1][3]));
}

// scores+softmax, 512 threads: thread (i=t>>4, j=t&15) covers (i,j) and (i,j+16).
// Qm,Km in LDS ld 132. No internal sync; caller syncs around.
static __device__ __forceinline__ void scores_softmax512(const float* __restrict__ Qm,
                                                         const float* __restrict__ Km,
                                                         float scale,
                                                         float* __restrict__ w_lds,
                                                         float* __restrict__ w_out,
                                                         int i, int j)
{
    float s0 = 0.f, s1 = 0.f;
    #pragma unroll 4
    for (int k=0;k<128;k+=4){
        float4 qv = ld4(Qm + i*132 + k);
        float4 k0 = ld4(Km + j*132 + k);
        float4 k1 = ld4(Km + (j+16)*132 + k);
        s0 += qv.x*k0.x + qv.y*k0.y + qv.z*k0.z + qv.w*k0.w;
        s1 += qv.x*k1.x + qv.y*k1.y + qv.z*k1.z + qv.w*k1.w;
    }
    s0 *= scale; s1 *= scale;
    float m = fmaxf(s0, s1);
    #pragma unroll
    for (int d=1; d<16; d<<=1) m = fmaxf(m, __shfl_xor(m, d));
    float e0 = expf(s0 - m), e1 = expf(s1 - m);
    float sum = e0 + e1;
    #pragma unroll
    for (int d=1; d<16; d<<=1) sum += __shfl_xor(sum, d);
    float inv = 1.f / sum;
    e0 *= inv; e1 *= inv;
    w_lds[i*36 + j]      = e0;
    w_lds[i*36 + j + 16] = e1;
    w_out[i*32 + j]      = e0;
    w_out[i*32 + j + 16] = e1;
}

// ===================== fused main kernel (one block per batch, 512 threads) =====================
__global__ __launch_bounds__(512)
void k_main(const float* __restrict__ states, const float* __restrict__ pol,
            const float* __restrict__ act,
            const float* __restrict__ Wkp, const float* __restrict__ Wqp,
            const float* __restrict__ Wvp, const float* __restrict__ Wk,
            const float* __restrict__ Wq,
            const float* __restrict__ WA, const float* __restrict__ WB,
            const float* __restrict__ W2,
            float* __restrict__ out_v, float* __restrict__ out_w1,
            float* __restrict__ out_w2)
{
    const int b = blockIdx.x;
    const int t = threadIdx.x;
    const float scale = 0.08838834764831845f;  // 1/sqrt(128)

    __shared__ float SH[14976];   // 59.9 KB
    float* Sst = SH;              // states tile 32x132
    float* B1  = SH + 4224;       // 32x132
    float* B2  = SH + 8448;       // 32x132
    float* Wb1 = SH + 12672;      // 32x36
    float* Wb2 = SH + 13824;      // 32x36  (end 14976)
    float* A1  = B1;              // 32x260 fp32 = 8320 floats, overlays B1+B2
    unsigned* P2 = (unsigned*)Sst; // 32x132 packed bf16 pairs
    unsigned* Q2 = (unsigned*)B1;

    const float* stg  = states + (size_t)b*(NN*DD);
    const float* actg = act + (size_t)b*(NN*NA);
    const float* polg = pol + (size_t)b*(NN*NA);

    // stage states
    #pragma unroll
    for (int u=0;u<2;u++){
        int i4 = t + 512*u;
        st4f(Sst + (i4>>5)*132 + (i4&31)*4, ld4(stg + i4*4));
    }
    __syncthreads();

    const int rg = t >> 5;          // 0..15
    const int c0 = (t & 31) * 4;    // 0..124
    const int r8 = t >> 6;          // 0..7
    const int c6 = (t & 63) * 4;    // 0..252
    const int si = t >> 4;          // 0..31
    const int sj = t & 15;          // 0..15

    // ---- q1,k1 = st@Wqp, st@Wkp ----
    float aq[2][4], ak[2][4];
    zero2(aq); zero2(ak);
    gemm2_dual<128>(Sst, 132, Wqp, Wkp, 128, aq, ak, rg, c0);
    store2(B1, aq, rg, c0); store2(B2, ak, rg, c0);
    __syncthreads();

    // ---- w1 = softmax(q1@k1^T * scale) ----
    scores_softmax512(B1, B2, scale, Wb1, out_w1 + (size_t)b*1024, si, sj);
    __syncthreads();

    // ---- u = w1@st -> B1 ----
    {
        float au[2][4]; zero2(au);
        gemm2<32>(Wb1, 36, Sst, 132, au, rg, c0);
        store2(B1, au, rg, c0);   // q1 dead, no readers of B1 in this phase
    }
    __syncthreads();

    // ---- wav1 = u@Wvp -> B2 ----
    {
        float aw[2][4]; zero2(aw);
        gemm2<128>(B1, 132, Wvp, 128, aw, rg, c0);
        store2(B2, aw, rg, c0);   // k1 dead
    }
    __syncthreads();

    // ---- q2,k2 = wav1@Wq, wav1@Wk (regs; sync; then store over u/wav1) ----
    zero2(aq); zero2(ak);
    gemm2_dual<128>(B2, 132, Wq, Wk, 128, aq, ak, rg, c0);
    __syncthreads();              // all wav1 reads complete
    store2(B1, aq, rg, c0); store2(B2, ak, rg, c0);
    __syncthreads();

    // ---- w2 = softmax(q2@k2^T * scale) ----
    scores_softmax512(B1, B2, scale, Wb2, out_w2 + (size_t)b*1024, si, sj);
    __syncthreads();

    // ---- A1 = st@WA + act@WB  [32][256] -> LDS (over B1+B2; q2/k2 dead) ----
    {
        float aA[4][4]; zero4(aA);
        gemm4<128>(Sst, 132, WA, 256, aA, r8, c6);
        gemm4<16>(actg, 16, WB, 256, aA, r8, c6);
        #pragma unroll
        for (int u=0;u<4;u++){
            int row = r8 + 8*u;
            st4f(A1 + row*260 + c6, make_float4(aA[u][0],aA[u][1],aA[u][2],aA[u][3]));
        }
    }
    __syncthreads();

    // ---- P = w2@A1 -> bf16 pack -> P2 (Sst region; Sst dead) ----
    {
        float aP[4][4]; zero4(aP);
        gemm4<32>(Wb2, 36, A1, 260, aP, r8, c6);
        #pragma unroll
        for (int u=0;u<4;u++){
            int row = r8 + 8*u;
            uint2 pp; pp.x = pack2(aP[u][0], aP[u][1]); pp.y = pack2(aP[u][2], aP[u][3]);
            *reinterpret_cast<uint2*>(P2 + row*132 + (c6>>1)) = pp;
        }
    }
    __syncthreads();

    // ---- Q = (pol-act)@WB -> bf16 pack -> Q2 (B1 region; A1 dead) ----
    {
        float aQ[4][4]; zero4(aQ);
        gemm4_diff<16>(polg, actg, 16, WB, 256, aQ, r8, c6);
        #pragma unroll
        for (int u=0;u<4;u++){
            int row = r8 + 8*u;
            uint2 qq; qq.x = pack2(aQ[u][0], aQ[u][1]); qq.y = pack2(aQ[u][2], aQ[u][3]);
            *reinterpret_cast<uint2*>(Q2 + row*132 + (c6>>1)) = qq;
        }
    }
    __syncthreads();

    // ---- value[i,j] = sum_h W2[h] * leaky(P[i,h] + w2[i,j]*Q[j,h]) ----
    {
        float w00 = Wb2[si*36 + sj], w01 = Wb2[si*36 + sj + 16];
        float a0 = 0.f, a1 = 0.f;

        #define STEP(P_, Q_, W_, W2H, ACC) {                       \
            float t_ = fmaf((W_), (Q_), (P_));                     \
            float u_ = fmaf(0.495f, fabsf(t_), 0.505f * t_);       \
            (ACC) = fmaf(u_, (W2H), (ACC)); }

        #pragma unroll 8
        for (int hp=0; hp<128; hp++){
            unsigned pa = P2[si*132 + hp];
            unsigned qa = Q2[sj*132 + hp];
            unsigned qb = Q2[(sj+16)*132 + hp];
            float w2e = W2[2*hp], w2o = W2[2*hp+1];   // uniform -> scalar loads
            float paE = __uint_as_float(pa<<16), paO = __uint_as_float(pa & 0xffff0000u);
            float qaE = __uint_as_float(qa<<16), qaO = __uint_as_float(qa & 0xffff0000u);
            float qbE = __uint_as_float(qb<<16), qbO = __uint_as_float(qb & 0xffff0000u);
            STEP(paE, qaE, w00, w2e, a0)  STEP(paO, qaO, w00, w2o, a0)
            STEP(paE, qbE, w01, w2e, a1)  STEP(paO, qbO, w01, w2o, a1)
        }
        #undef STEP

        float* ov = out_v + (size_t)b*1024;
        ov[si*32 + sj]      = a0;
        ov[si*32 + sj + 16] = a1;
    }
}

extern "C" void kernel_launch(void* const* d_in, const int* in_sizes, int n_in,
                              void* d_out, int out_size, void* d_ws, size_t ws_size,
                              hipStream_t stream) {
    const float* states = (const float*)d_in[0];
    const float* pol    = (const float*)d_in[1];
    const float* act    = (const float*)d_in[2];
    const float* Wkp    = (const float*)d_in[3];
    const float* Wqp    = (const float*)d_in[4];
    const float* Wvp    = (const float*)d_in[5];
    const float* Wk     = (const float*)d_in[6];
    const float* Wq     = (const float*)d_in[7];
    const float* We     = (const float*)d_in[8];
    const float* Wav    = (const float*)d_in[9];
    const float* W1     = (const float*)d_in[10];
    const float* W2     = (const float*)d_in[11];

    float* out    = (float*)d_out;
    float* out_v  = out;                 // [256,32,32,1]
    float* out_w1 = out + 256*1024;      // [256,32,32]
    float* out_w2 = out + 2*256*1024;    // [256,32,32]

    float* wsWavW1 = (float*)d_ws;            // [128][256]
    float* wsWA    = wsWavW1 + 128*256;       // [128][256]
    float* wsWB    = wsWA + 128*256;          // [16][256]

    hipLaunchKernelGGL(k_pre1, dim3(8), dim3(256), 0, stream, Wav, W1, wsWavW1);
    hipLaunchKernelGGL(k_pre2, dim3(9), dim3(256), 0, stream, We, wsWavW1, wsWA, wsWB);
    hipLaunchKernelGGL(k_main, dim3(NB), dim3(512), 0, stream,
                       states, pol, act, Wkp, Wqp, Wvp, Wk, Wq,
                       wsWA, wsWB, W2, out_v, out_w1, out_w2);
}

// Round 4
// 98.983 us; speedup vs baseline: 1.0363x; 1.0363x over previous
//
#include <hip/hip_runtime.h>
#include <math.h>

// Problem constants
#define NB 256   // batches
#define NN 32    // agents
#define DD 128   // state dim
#define NA 16    // action dim
#define HH 256   // hidden

static __device__ __forceinline__ float4 ld4(const float* p){ return *reinterpret_cast<const float4*>(p); }
static __device__ __forceinline__ void st4f(float* p, float4 v){ *reinterpret_cast<float4*>(p) = v; }
static __device__ __forceinline__ float elem(float4 v, int kk){
    return (kk==0)?v.x:(kk==1)?v.y:(kk==2)?v.z:v.w;
}

static __device__ __forceinline__ unsigned f2bf(float x){
    unsigned u = __float_as_uint(x);
    u += 0x7fffu + ((u >> 16) & 1u);   // round-to-nearest-even
    return u >> 16;
}
static __device__ __forceinline__ unsigned pack2(float a, float b){
    return f2bf(a) | (f2bf(b) << 16);
}

// ============ merged pre-kernel: WAB = (We @ Wav) @ W1  [144][256] ============
// blocks 0..7: 32-row tiles of We[:128] x 2 col-halves; block 8: rows 128..143 full width.
__global__ __launch_bounds__(256)
void k_pre(const float* __restrict__ We, const float* __restrict__ Wav,
           const float* __restrict__ W1, float* __restrict__ WAB)
{
    __shared__ float Xs[32*132];
    __shared__ float Ts[32*132];
    const int t = threadIdx.x;
    const int bid = blockIdx.x;

    if (bid < 8) {
        const int rt = bid >> 1, ch = bid & 1;
        const int rowbase = rt * 32;
        // stage We rows [rowbase, rowbase+32)
        #pragma unroll
        for (int u = 0; u < 4; u++) {
            int i4 = t + 256*u;
            st4f(Xs + (i4>>5)*132 + (i4&31)*4, ld4(We + rowbase*128 + i4*4));
        }
        __syncthreads();
        const int c = t & 127, g = t >> 7;   // g: 0..1, 16 rows each
        {
            float acc[16];
            #pragma unroll
            for (int u=0;u<16;u++) acc[u]=0.f;
            const float* wv = Wav + c;
            #pragma unroll 2
            for (int k0=0;k0<128;k0+=4){
                float4 xv[16];
                #pragma unroll
                for (int u=0;u<16;u++) xv[u] = ld4(Xs + (g*16+u)*132 + k0);
                #pragma unroll
                for (int kk=0;kk<4;kk++){
                    float w = wv[(k0+kk)*128];
                    #pragma unroll
                    for (int u=0;u<16;u++) acc[u] = fmaf(elem(xv[u],kk), w, acc[u]);
                }
            }
            #pragma unroll
            for (int u=0;u<16;u++) Ts[(g*16+u)*132 + c] = acc[u];
        }
        __syncthreads();
        {
            float acc[16];
            #pragma unroll
            for (int u=0;u<16;u++) acc[u]=0.f;
            const float* w1p = W1 + ch*128 + c;
            #pragma unroll 2
            for (int k0=0;k0<128;k0+=4){
                float4 xv[16];
                #pragma unroll
                for (int u=0;u<16;u++) xv[u] = ld4(Ts + (g*16+u)*132 + k0);
                #pragma unroll
                for (int kk=0;kk<4;kk++){
                    float w = w1p[(k0+kk)*256];
                    #pragma unroll
                    for (int u=0;u<16;u++) acc[u] = fmaf(elem(xv[u],kk), w, acc[u]);
                }
            }
            #pragma unroll
            for (int u=0;u<16;u++)
                WAB[(rowbase + g*16 + u)*256 + ch*128 + c] = acc[u];
        }
    } else {
        // rows 128..143 (the WB part), 16 rows, full 256 cols
        #pragma unroll
        for (int u = 0; u < 2; u++) {
            int i4 = t + 256*u;
            st4f(Xs + (i4>>5)*132 + (i4&31)*4, ld4(We + 128*128 + i4*4));
        }
        __syncthreads();
        const int c = t & 127, g = t >> 7;   // 8 rows each
        {
            float acc[8];
            #pragma unroll
            for (int u=0;u<8;u++) acc[u]=0.f;
            const float* wv = Wav + c;
            #pragma unroll 2
            for (int k0=0;k0<128;k0+=4){
                float4 xv[8];
                #pragma unroll
                for (int u=0;u<8;u++) xv[u] = ld4(Xs + (g*8+u)*132 + k0);
                #pragma unroll
                for (int kk=0;kk<4;kk++){
                    float w = wv[(k0+kk)*128];
                    #pragma unroll
                    for (int u=0;u<8;u++) acc[u] = fmaf(elem(xv[u],kk), w, acc[u]);
                }
            }
            #pragma unroll
            for (int u=0;u<8;u++) Ts[(g*8+u)*132 + c] = acc[u];
        }
        __syncthreads();
        {
            float acc[16];
            #pragma unroll
            for (int u=0;u<16;u++) acc[u]=0.f;
            const float* w1p = W1 + t;           // one col per thread (256 cols)
            #pragma unroll 2
            for (int k0=0;k0<128;k0+=4){
                float4 xv[16];
                #pragma unroll
                for (int u=0;u<16;u++) xv[u] = ld4(Ts + u*132 + k0);
                #pragma unroll
                for (int kk=0;kk<4;kk++){
                    float w = w1p[(k0+kk)*256];
                    #pragma unroll
                    for (int u=0;u<16;u++) acc[u] = fmaf(elem(xv[u],kk), w, acc[u]);
                }
            }
            #pragma unroll
            for (int u=0;u<16;u++)
                WAB[(128 + u)*256 + t] = acc[u];
        }
    }
}

// scores+softmax, 512 threads: thread (i=t>>4, j=t&15) covers (i,j) and (i,j+16).
static __device__ __forceinline__ void scores_softmax512(const float* __restrict__ Qm,
                                                         const float* __restrict__ Km,
                                                         float scale,
                                                         float* __restrict__ w_lds,
                                                         float* __restrict__ w_out,
                                                         int i, int j)
{
    float s0 = 0.f, s1 = 0.f;
    #pragma unroll 4
    for (int k=0;k<128;k+=4){
        float4 qv = ld4(Qm + i*132 + k);
        float4 k0 = ld4(Km + j*132 + k);
        float4 k1 = ld4(Km + (j+16)*132 + k);
        s0 += qv.x*k0.x + qv.y*k0.y + qv.z*k0.z + qv.w*k0.w;
        s1 += qv.x*k1.x + qv.y*k1.y + qv.z*k1.z + qv.w*k1.w;
    }
    s0 *= scale; s1 *= scale;
    float m = fmaxf(s0, s1);
    #pragma unroll
    for (int d=1; d<16; d<<=1) m = fmaxf(m, __shfl_xor(m, d));
    float e0 = expf(s0 - m), e1 = expf(s1 - m);
    float sum = e0 + e1;
    #pragma unroll
    for (int d=1; d<16; d<<=1) sum += __shfl_xor(sum, d);
    float inv = 1.f / sum;
    e0 *= inv; e1 *= inv;
    w_lds[i*36 + j]      = e0;
    w_lds[i*36 + j + 16] = e1;
    w_out[i*32 + j]      = e0;
    w_out[i*32 + j + 16] = e1;
}

// ============ fused main kernel: one block per batch, 512 threads ============
// Column-in-register GEMMs: thread owns col c (lane-coalesced W reads),
// X rows are wave-uniform LDS broadcasts.
__global__ __launch_bounds__(512)
void k_main(const float* __restrict__ states, const float* __restrict__ pol,
            const float* __restrict__ act,
            const float* __restrict__ Wkp, const float* __restrict__ Wqp,
            const float* __restrict__ Wvp, const float* __restrict__ Wk,
            const float* __restrict__ Wq,
            const float* __restrict__ WAB, const float* __restrict__ W2,
            float* __restrict__ out_v, float* __restrict__ out_w1,
            float* __restrict__ out_w2)
{
    const int b = blockIdx.x;
    const int t = threadIdx.x;
    const float scale = 0.08838834764831845f;  // 1/sqrt(128)

    __shared__ float SH[16000];   // 62.5 KB
    float* Sst = SH;              // states 32x132
    float* B1  = SH + 4224;       // 32x132
    float* B2  = SH + 8448;       // 32x132
    float* Wb1 = SH + 12672;      // 32x36
    float* Wb2 = SH + 13824;      // 32x36
    float* APa = SH + 14976;      // act  [32][16]
    float* APd = SH + 15488;      // pol-act [32][16]
    float* A1  = B1;              // 32x260 overlays B1+B2
    unsigned* P2 = (unsigned*)Sst;
    unsigned* Q2 = (unsigned*)B1;

    const float* stg  = states + (size_t)b*(NN*DD);
    const float* actg = act + (size_t)b*(NN*NA);
    const float* polg = pol + (size_t)b*(NN*NA);

    // ---- stage states + act + (pol-act) ----
    #pragma unroll
    for (int u=0;u<2;u++){
        int i4 = t + 512*u;
        st4f(Sst + (i4>>5)*132 + (i4&31)*4, ld4(stg + i4*4));
    }
    if (t < 128) {
        int r = t>>2, cc = (t&3)*4;
        st4f(APa + r*16 + cc, ld4(actg + r*16 + cc));
    } else if (t < 256) {
        int t2 = t-128, r = t2>>2, cc = (t2&3)*4;
        float4 p = ld4(polg + r*16 + cc), a = ld4(actg + r*16 + cc);
        st4f(APd + r*16 + cc, make_float4(p.x-a.x, p.y-a.y, p.z-a.z, p.w-a.w));
    }
    __syncthreads();

    const int c  = t & 127;      // column for 128-col gemms
    const int g  = t >> 7;       // 0..3 -> rows g*8..g*8+7
    const int c2 = t & 255;      // column for 256-col gemm
    const int g2 = t >> 8;       // 0..1 -> rows g2*16..g2*16+15
    const int cp = (t & 127)*2;  // paired cols for P/Q phases
    const int si = t >> 4;       // 0..31
    const int sj = t & 15;       // 0..15

    // ---- P1: q1 = st@Wqp, k1 = st@Wkp (dual, shared X reads) ----
    {
        float aq[8], ak[8];
        #pragma unroll
        for (int u=0;u<8;u++){ aq[u]=0.f; ak[u]=0.f; }
        const float* wqp = Wqp + c;
        const float* wkp = Wkp + c;
        #pragma unroll 2
        for (int k0=0;k0<128;k0+=4){
            float4 xv[8];
            #pragma unroll
            for (int u=0;u<8;u++) xv[u] = ld4(Sst + (g*8+u)*132 + k0);
            #pragma unroll
            for (int kk=0;kk<4;kk++){
                float wq = wqp[(k0+kk)*128];
                float wk = wkp[(k0+kk)*128];
                #pragma unroll
                for (int u=0;u<8;u++){
                    float x = elem(xv[u],kk);
                    aq[u] = fmaf(x, wq, aq[u]);
                    ak[u] = fmaf(x, wk, ak[u]);
                }
            }
        }
        #pragma unroll
        for (int u=0;u<8;u++){
            B1[(g*8+u)*132 + c] = aq[u];
            B2[(g*8+u)*132 + c] = ak[u];
        }
    }
    __syncthreads();

    // ---- P2: w1 = softmax(q1@k1^T * scale) ----
    scores_softmax512(B1, B2, scale, Wb1, out_w1 + (size_t)b*1024, si, sj);
    __syncthreads();

    // ---- P3: u = w1@st -> B1 (K=32; W operand = Sst, per-lane reads) ----
    {
        float au[8];
        #pragma unroll
        for (int u=0;u<8;u++) au[u]=0.f;
        #pragma unroll
        for (int k0=0;k0<32;k0+=4){
            float4 xv[8];
            #pragma unroll
            for (int u=0;u<8;u++) xv[u] = ld4(Wb1 + (g*8+u)*36 + k0);
            #pragma unroll
            for (int kk=0;kk<4;kk++){
                float w = Sst[(k0+kk)*132 + c];
                #pragma unroll
                for (int u=0;u<8;u++) au[u] = fmaf(elem(xv[u],kk), w, au[u]);
            }
        }
        #pragma unroll
        for (int u=0;u<8;u++) B1[(g*8+u)*132 + c] = au[u];
    }
    __syncthreads();

    // ---- P4: wav1 = u@Wvp -> B2 ----
    {
        float aw[8];
        #pragma unroll
        for (int u=0;u<8;u++) aw[u]=0.f;
        const float* wvp = Wvp + c;
        #pragma unroll 2
        for (int k0=0;k0<128;k0+=4){
            float4 xv[8];
            #pragma unroll
            for (int u=0;u<8;u++) xv[u] = ld4(B1 + (g*8+u)*132 + k0);
            #pragma unroll
            for (int kk=0;kk<4;kk++){
                float w = wvp[(k0+kk)*128];
                #pragma unroll
                for (int u=0;u<8;u++) aw[u] = fmaf(elem(xv[u],kk), w, aw[u]);
            }
        }
        #pragma unroll
        for (int u=0;u<8;u++) B2[(g*8+u)*132 + c] = aw[u];
    }
    __syncthreads();

    // ---- P5: q2 = wav1@Wq, k2 = wav1@Wk (regs; sync; store over B1/B2) ----
    {
        float aq[8], ak[8];
        #pragma unroll
        for (int u=0;u<8;u++){ aq[u]=0.f; ak[u]=0.f; }
        const float* wqq = Wq + c;
        const float* wkk = Wk + c;
        #pragma unroll 2
        for (int k0=0;k0<128;k0+=4){
            float4 xv[8];
            #pragma unroll
            for (int u=0;u<8;u++) xv[u] = ld4(B2 + (g*8+u)*132 + k0);
            #pragma unroll
            for (int kk=0;kk<4;kk++){
                float wq = wqq[(k0+kk)*128];
                float wk = wkk[(k0+kk)*128];
                #pragma unroll
                for (int u=0;u<8;u++){
                    float x = elem(xv[u],kk);
                    aq[u] = fmaf(x, wq, aq[u]);
                    ak[u] = fmaf(x, wk, ak[u]);
                }
            }
        }
        __syncthreads();   // all B2 reads done
        #pragma unroll
        for (int u=0;u<8;u++){
            B1[(g*8+u)*132 + c] = aq[u];
            B2[(g*8+u)*132 + c] = ak[u];
        }
    }
    __syncthreads();

    // ---- P6: w2 = softmax(q2@k2^T * scale) ----
    scores_softmax512(B1, B2, scale, Wb2, out_w2 + (size_t)b*1024, si, sj);
    __syncthreads();

    // ---- P7: A1 = st@WA + act@WB  [32][256] -> LDS over B1+B2 ----
    {
        float aa[16];
        #pragma unroll
        for (int u=0;u<16;u++) aa[u]=0.f;
        const float* wA = WAB + c2;            // rows 0..127
        #pragma unroll 2
        for (int k0=0;k0<128;k0+=4){
            float4 xv[16];
            #pragma unroll
            for (int u=0;u<16;u++) xv[u] = ld4(Sst + (g2*16+u)*132 + k0);
            #pragma unroll
            for (int kk=0;kk<4;kk++){
                float w = wA[(k0+kk)*256];
                #pragma unroll
                for (int u=0;u<16;u++) aa[u] = fmaf(elem(xv[u],kk), w, aa[u]);
            }
        }
        const float* wB = WAB + 128*256 + c2;  // rows 128..143
        #pragma unroll
        for (int k0=0;k0<16;k0+=4){
            float4 xv[16];
            #pragma unroll
            for (int u=0;u<16;u++) xv[u] = ld4(APa + (g2*16+u)*16 + k0);
            #pragma unroll
            for (int kk=0;kk<4;kk++){
                float w = wB[(k0+kk)*256];
                #pragma unroll
                for (int u=0;u<16;u++) aa[u] = fmaf(elem(xv[u],kk), w, aa[u]);
            }
        }
        #pragma unroll
        for (int u=0;u<16;u++) A1[(g2*16+u)*260 + c2] = aa[u];
    }
    __syncthreads();

    // ---- P8: P = w2@A1 (K=32) -> bf16 pack -> P2 (over Sst) ----
    {
        float ap0[8], ap1[8];
        #pragma unroll
        for (int u=0;u<8;u++){ ap0[u]=0.f; ap1[u]=0.f; }
        #pragma unroll
        for (int k0=0;k0<32;k0+=4){
            float4 xv[8];
            #pragma unroll
            for (int u=0;u<8;u++) xv[u] = ld4(Wb2 + (g*8+u)*36 + k0);
            #pragma unroll
            for (int kk=0;kk<4;kk++){
                float2 w = *reinterpret_cast<const float2*>(A1 + (k0+kk)*260 + cp);
                #pragma unroll
                for (int u=0;u<8;u++){
                    float x = elem(xv[u],kk);
                    ap0[u] = fmaf(x, w.x, ap0[u]);
                    ap1[u] = fmaf(x, w.y, ap1[u]);
                }
            }
        }
        #pragma unroll
        for (int u=0;u<8;u++)
            P2[(g*8+u)*132 + (cp>>1)] = pack2(ap0[u], ap1[u]);
    }
    __syncthreads();

    // ---- P9: Q = (pol-act)@WB (K=16) -> bf16 pack -> Q2 (over B1/A1) ----
    {
        float aq0[8], aq1[8];
        #pragma unroll
        for (int u=0;u<8;u++){ aq0[u]=0.f; aq1[u]=0.f; }
        const float* wB = WAB + 128*256;
        #pragma unroll
        for (int k0=0;k0<16;k0+=4){
            float4 xv[8];
            #pragma unroll
            for (int u=0;u<8;u++) xv[u] = ld4(APd + (g*8+u)*16 + k0);
            #pragma unroll
            for (int kk=0;kk<4;kk++){
                float2 w = *reinterpret_cast<const float2*>(wB + (k0+kk)*256 + cp);
                #pragma unroll
                for (int u=0;u<8;u++){
                    float x = elem(xv[u],kk);
                    aq0[u] = fmaf(x, w.x, aq0[u]);
                    aq1[u] = fmaf(x, w.y, aq1[u]);
                }
            }
        }
        #pragma unroll
        for (int u=0;u<8;u++)
            Q2[(g*8+u)*132 + (cp>>1)] = pack2(aq0[u], aq1[u]);
    }
    __syncthreads();

    // ---- P10: value[i,j] = sum_h W2[h] * leaky(P[i,h] + w2[i,j]*Q[j,h]) ----
    {
        float w00 = Wb2[si*36 + sj], w01 = Wb2[si*36 + sj + 16];
        float a0 = 0.f, a1 = 0.f;

        #define STEP(P_, Q_, W_, W2H, ACC) {                       \
            float t_ = fmaf((W_), (Q_), (P_));                     \
            float u_ = fmaf(0.495f, fabsf(t_), 0.505f * t_);       \
            (ACC) = fmaf(u_, (W2H), (ACC)); }

        #pragma unroll 8
        for (int hp=0; hp<128; hp++){
            unsigned pa = P2[si*132 + hp];
            unsigned qa = Q2[sj*132 + hp];
            unsigned qb = Q2[(sj+16)*132 + hp];
            float w2e = W2[2*hp], w2o = W2[2*hp+1];   // uniform -> scalar loads
            float paE = __uint_as_float(pa<<16), paO = __uint_as_float(pa & 0xffff0000u);
            float qaE = __uint_as_float(qa<<16), qaO = __uint_as_float(qa & 0xffff0000u);
            float qbE = __uint_as_float(qb<<16), qbO = __uint_as_float(qb & 0xffff0000u);
            STEP(paE, qaE, w00, w2e, a0)  STEP(paO, qaO, w00, w2o, a0)
            STEP(paE, qbE, w01, w2e, a1)  STEP(paO, qbO, w01, w2o, a1)
        }
        #undef STEP

        float* ov = out_v + (size_t)b*1024;
        ov[si*32 + sj]      = a0;
        ov[si*32 + sj + 16] = a1;
    }
}

extern "C" void kernel_launch(void* const* d_in, const int* in_sizes, int n_in,
                              void* d_out, int out_size, void* d_ws, size_t ws_size,
                              hipStream_t stream) {
    const float* states = (const float*)d_in[0];
    const float* pol    = (const float*)d_in[1];
    const float* act    = (const float*)d_in[2];
    const float* Wkp    = (const float*)d_in[3];
    const float* Wqp    = (const float*)d_in[4];
    const float* Wvp    = (const float*)d_in[5];
    const float* Wk     = (const float*)d_in[6];
    const float* Wq     = (const float*)d_in[7];
    const float* We     = (const float*)d_in[8];
    const float* Wav    = (const float*)d_in[9];
    const float* W1     = (const float*)d_in[10];
    const float* W2     = (const float*)d_in[11];

    float* out    = (float*)d_out;
    float* out_v  = out;                 // [256,32,32,1]
    float* out_w1 = out + 256*1024;      // [256,32,32]
    float* out_w2 = out + 2*256*1024;    // [256,32,32]

    float* wsWAB = (float*)d_ws;         // [144][256]

    hipLaunchKernelGGL(k_pre, dim3(9), dim3(256), 0, stream, We, Wav, W1, wsWAB);
    hipLaunchKernelGGL(k_main, dim3(NB), dim3(512), 0, stream,
                       states, pol, act, Wkp, Wqp, Wvp, Wk, Wq,
                       wsWAB, W2, out_v, out_w1, out_w2);
}

// Round 5
// 62.813 us; speedup vs baseline: 1.6331x; 1.5758x over previous
//
#include <hip/hip_runtime.h>
#include <math.h>

// Problem constants
#define NB 256   // batches
#define NN 32    // agents
#define DD 128   // state dim
#define NA 16    // action dim
#define HH 256   // hidden

using f32x4v  = __attribute__((ext_vector_type(4))) float;
using bf16x8  = __attribute__((ext_vector_type(8))) short;

static __device__ __forceinline__ float4 ld4(const float* p){ return *reinterpret_cast<const float4*>(p); }
static __device__ __forceinline__ void st4f(float* p, float4 v){ *reinterpret_cast<float4*>(p) = v; }
static __device__ __forceinline__ float elem(float4 v, int kk){
    return (kk==0)?v.x:(kk==1)?v.y:(kk==2)?v.z:v.w;
}

static __device__ __forceinline__ unsigned f2bf(float x){
    unsigned u = __float_as_uint(x);
    u += 0x7fffu + ((u >> 16) & 1u);   // round-to-nearest-even
    return u >> 16;
}
static __device__ __forceinline__ unsigned pack2(float a, float b){
    return f2bf(a) | (f2bf(b) << 16);
}
static __device__ __forceinline__ float bf2f(unsigned short s){
    return __uint_as_float(((unsigned)s) << 16);
}

static __device__ __forceinline__ f32x4v mfma16(bf16x8 a, bf16x8 b, f32x4v c){
    return __builtin_amdgcn_mfma_f32_16x16x32_bf16(a, b, c, 0, 0, 0);
}

// write one B-fragment (16 bf16 bytes per lane) to the swizzled weight buffer
static __device__ __forceinline__ void store_frag(unsigned short* __restrict__ dst,
                                                  int frag, int l, const float v[8]){
    uint4 p;
    p.x = pack2(v[0], v[1]); p.y = pack2(v[2], v[3]);
    p.z = pack2(v[4], v[5]); p.w = pack2(v[6], v[7]);
    *reinterpret_cast<uint4*>(dst + (size_t)(frag*64 + l)*8) = p;
}

// =============================================================================
// k_pre: WAB = (We @ Wav) @ W1 [144][256] (fp32 rows 128..143 kept for P9) +
// fragment-swizzled bf16 copies of WAB (padded to K=160) and the 5 attention
// weights (128x128). Swizzle layout per MFMA B-frag (16x16x32):
//   frag (kt,nt): lane l holds B[kt*32+(l>>4)*8+i][nt*16+(l&15)], i=0..7.
// blocks 0..7: WAB rows rt*32 x col-half; block 8: WAB rows 128..143 (+zeros);
// blocks 9..18: attention weights (2 blocks each).
// =============================================================================
__global__ __launch_bounds__(256)
void k_pre(const float* __restrict__ We, const float* __restrict__ Wav,
           const float* __restrict__ W1,
           const float* __restrict__ Wqp, const float* __restrict__ Wkp,
           const float* __restrict__ Wvp, const float* __restrict__ Wq,
           const float* __restrict__ Wk,
           float* __restrict__ WABf, unsigned short* __restrict__ WABs,
           unsigned short* __restrict__ Wqps, unsigned short* __restrict__ Wkps,
           unsigned short* __restrict__ Wvps, unsigned short* __restrict__ Wqs,
           unsigned short* __restrict__ Wks)
{
    __shared__ float Xs[32*132];
    __shared__ float Ts[32*132];
    const int t = threadIdx.x;
    const int bid = blockIdx.x;

    if (bid < 8) {
        const int rt = bid >> 1, ch = bid & 1;
        const int rowbase = rt * 32;
        // stage We rows
        #pragma unroll
        for (int u = 0; u < 4; u++) {
            int i4 = t + 256*u;
            st4f(Xs + (i4>>5)*132 + (i4&31)*4, ld4(We + rowbase*128 + i4*4));
        }
        __syncthreads();
        const int c = t & 127, g = t >> 7;   // g: 0..1, 16 rows each
        {   // T = tile @ Wav
            float acc[16];
            #pragma unroll
            for (int u=0;u<16;u++) acc[u]=0.f;
            const float* wv = Wav + c;
            #pragma unroll 2
            for (int k0=0;k0<128;k0+=4){
                float4 xv[16];
                #pragma unroll
                for (int u=0;u<16;u++) xv[u] = ld4(Xs + (g*16+u)*132 + k0);
                #pragma unroll
                for (int kk=0;kk<4;kk++){
                    float w = wv[(k0+kk)*128];
                    #pragma unroll
                    for (int u=0;u<16;u++) acc[u] = fmaf(elem(xv[u],kk), w, acc[u]);
                }
            }
            #pragma unroll
            for (int u=0;u<16;u++) Ts[(g*16+u)*132 + c] = acc[u];
        }
        __syncthreads();
        {   // WAB-tile = T @ W1(col half) -> Xs
            float acc[16];
            #pragma unroll
            for (int u=0;u<16;u++) acc[u]=0.f;
            const float* w1p = W1 + ch*128 + c;
            #pragma unroll 2
            for (int k0=0;k0<128;k0+=4){
                float4 xv[16];
                #pragma unroll
                for (int u=0;u<16;u++) xv[u] = ld4(Ts + (g*16+u)*132 + k0);
                #pragma unroll
                for (int kk=0;kk<4;kk++){
                    float w = w1p[(k0+kk)*256];
                    #pragma unroll
                    for (int u=0;u<16;u++) acc[u] = fmaf(elem(xv[u],kk), w, acc[u]);
                }
            }
            #pragma unroll
            for (int u=0;u<16;u++) Xs[(g*16+u)*132 + c] = acc[u];
        }
        __syncthreads();
        // swizzle: kt = rt, nt = ch*8 + f, f = 0..7 (512 lane-slots)
        #pragma unroll
        for (int ss = 0; ss < 2; ss++){
            int s = t + 256*ss;
            int f = s >> 6, l = s & 63;
            float v[8];
            #pragma unroll
            for (int i=0;i<8;i++)
                v[i] = Xs[((l>>4)*8 + i)*132 + f*16 + (l&15)];
            store_frag(WABs, rt*16 + ch*8 + f, l, v);
        }
    } else if (bid == 8) {
        // WAB rows 128..143 (full 256 cols), zero-pad k to 160
        #pragma unroll
        for (int u = 0; u < 2; u++) {
            int i4 = t + 256*u;
            st4f(Xs + (i4>>5)*132 + (i4&31)*4, ld4(We + 128*128 + i4*4));
        }
        __syncthreads();
        const int c = t & 127, g = t >> 7;
        {
            float acc[8];
            #pragma unroll
            for (int u=0;u<8;u++) acc[u]=0.f;
            const float* wv = Wav + c;
            #pragma unroll 2
            for (int k0=0;k0<128;k0+=4){
                float4 xv[8];
                #pragma unroll
                for (int u=0;u<8;u++) xv[u] = ld4(Xs + (g*8+u)*132 + k0);
                #pragma unroll
                for (int kk=0;kk<4;kk++){
                    float w = wv[(k0+kk)*128];
                    #pragma unroll
                    for (int u=0;u<8;u++) acc[u] = fmaf(elem(xv[u],kk), w, acc[u]);
                }
            }
            #pragma unroll
            for (int u=0;u<8;u++) Ts[(g*8+u)*132 + c] = acc[u];
        }
        __syncthreads();
        {
            float acc[16];
            #pragma unroll
            for (int u=0;u<16;u++) acc[u]=0.f;
            const float* w1p = W1 + t;           // one col per thread
            #pragma unroll 2
            for (int k0=0;k0<128;k0+=4){
                float4 xv[16];
                #pragma unroll
                for (int u=0;u<16;u++) xv[u] = ld4(Ts + u*132 + k0);
                #pragma unroll
                for (int kk=0;kk<4;kk++){
                    float w = w1p[(k0+kk)*256];
                    #pragma unroll
                    for (int u=0;u<16;u++) acc[u] = fmaf(elem(xv[u],kk), w, acc[u]);
                }
            }
            #pragma unroll
            for (int u=0;u<16;u++){
                WABf[(128 + u)*256 + t] = acc[u];   // fp32 WB for P9
                Xs[u*260 + t] = acc[u];
            }
        }
        __syncthreads();
        // swizzle kt=4: rows 128..143 real, 144..159 zero; 16 nt frags
        #pragma unroll
        for (int ss = 0; ss < 4; ss++){
            int s = t + 256*ss;
            int f = s >> 6, l = s & 63;
            float v[8];
            #pragma unroll
            for (int i=0;i<8;i++){
                int kidx = (l>>4)*8 + i;
                v[i] = (kidx < 16) ? Xs[kidx*260 + f*16 + (l&15)] : 0.f;
            }
            store_frag(WABs, 4*16 + f, l, v);
        }
    } else {
        // attention weights: sel = (bid-9)>>1, half = (bid-9)&1
        const int sel = (bid - 9) >> 1, half = (bid - 9) & 1;
        const float* W = (sel==0) ? Wqp : (sel==1) ? Wkp : (sel==2) ? Wvp :
                         (sel==3) ? Wq : Wk;
        unsigned short* dst = (sel==0) ? Wqps : (sel==1) ? Wkps : (sel==2) ? Wvps :
                              (sel==3) ? Wqs : Wks;
        #pragma unroll
        for (int ss = 0; ss < 4; ss++){
            int s = half*1024 + t + 256*ss;
            int frag = s >> 6, l = s & 63;
            int kt = frag >> 3, nt = frag & 7;
            float v[8];
            #pragma unroll
            for (int i=0;i<8;i++)
                v[i] = W[(kt*32 + (l>>4)*8 + i)*128 + nt*16 + (l&15)];
            store_frag(dst, frag, l, v);
        }
    }
}

// scores+softmax, 512 threads: thread (i=t>>4, j=t&15) covers (i,j) and (i,j+16).
static __device__ __forceinline__ void scores_softmax512(const float* __restrict__ Qm,
                                                         const float* __restrict__ Km,
                                                         float scale,
                                                         float* __restrict__ w_lds,
                                                         float* __restrict__ w_out,
                                                         int i, int j)
{
    float s0 = 0.f, s1 = 0.f;
    #pragma unroll 4
    for (int k=0;k<128;k+=4){
        float4 qv = ld4(Qm + i*132 + k);
        float4 k0 = ld4(Km + j*132 + k);
        float4 k1 = ld4(Km + (j+16)*132 + k);
        s0 += qv.x*k0.x + qv.y*k0.y + qv.z*k0.z + qv.w*k0.w;
        s1 += qv.x*k1.x + qv.y*k1.y + qv.z*k1.z + qv.w*k1.w;
    }
    s0 *= scale; s1 *= scale;
    float m = fmaxf(s0, s1);
    #pragma unroll
    for (int d=1; d<16; d<<=1) m = fmaxf(m, __shfl_xor(m, d));
    float e0 = expf(s0 - m), e1 = expf(s1 - m);
    float sum = e0 + e1;
    #pragma unroll
    for (int d=1; d<16; d<<=1) sum += __shfl_xor(sum, d);
    float inv = 1.f / sum;
    e0 *= inv; e1 *= inv;
    w_lds[i*36 + j]      = e0;
    w_lds[i*36 + j + 16] = e1;
    w_out[i*32 + j]      = e0;
    w_out[i*32 + j + 16] = e1;
}

// =============================================================================
// k_main: one block per batch, 512 threads (8 waves). Heavy GEMMs on MFMA.
// =============================================================================
__global__ __launch_bounds__(512)
void k_main(const float* __restrict__ states, const float* __restrict__ pol,
            const float* __restrict__ act,
            const unsigned short* __restrict__ Wqps, const unsigned short* __restrict__ Wkps,
            const unsigned short* __restrict__ Wvps, const unsigned short* __restrict__ Wqs,
            const unsigned short* __restrict__ Wks,  const unsigned short* __restrict__ WABs,
            const float* __restrict__ WABf, const float* __restrict__ W2,
            float* __restrict__ out_v, float* __restrict__ out_w1,
            float* __restrict__ out_w2)
{
    const int b = blockIdx.x;
    const int t = threadIdx.x;
    const float scale = 0.08838834764831845f;  // 1/sqrt(128)

    __shared__ float SH[16000];   // 62.5 KB
    float* B1   = SH;                                   // 32x132
    float* B2   = SH + 4224;                            // 32x132
    float* Wb2f = SH + 8448;                            // 32x36
    float* Wb1f = SH + 9600;                            // 32x36
    float* APd  = SH + 10752;                           // 32x16 (pol-act)
    unsigned short* Xoa  = (unsigned short*)(SH + 11264); // [32][168] bf16 (st|act|0)
    unsigned short* Ubf  = (unsigned short*)B1;           // [32][136] bf16
    unsigned short* Wvbf = (unsigned short*)B2;           // [32][136] bf16
    float*    A1 = SH;                                   // [32][260] fp32 (over B1+B2)
    unsigned* P2 = (unsigned*)(SH + 11904);              // [32][128] packed bf16 (over dead Xoa)
    unsigned* Q2 = (unsigned*)SH;                        // [32][130] packed bf16 (over dead A1)

    const float* stg  = states + (size_t)b*(NN*DD);
    const float* actg = act + (size_t)b*(NN*NA);
    const float* polg = pol + (size_t)b*(NN*NA);

    // ---- stage Xoa = bf16([st | act | 0]) (k 0..159), APd = pol-act ----
    {
        int r = t >> 4, kb = t & 15;
        #pragma unroll
        for (int uu = 0; uu < 10; uu++){
            int k = kb + 16*uu;
            float v = (k < 128) ? stg[r*128 + k]
                    : (k < 144) ? actg[r*16 + (k-128)] : 0.f;
            Xoa[r*168 + k] = (unsigned short)f2bf(v);
        }
        if (t < 128) {
            int rr = t>>2, cc = (t&3)*4;
            float4 p = ld4(polg + rr*16 + cc), a = ld4(actg + rr*16 + cc);
            st4f(APd + rr*16 + cc, make_float4(p.x-a.x, p.y-a.y, p.z-a.z, p.w-a.w));
        }
    }
    __syncthreads();

    // MFMA wave geometry
    const int l    = t & 63;
    const int wv   = t >> 6;             // wave 0..7
    const int mt   = wv & 1;             // M-tile
    const int ntb  = (wv >> 1) * 2;      // N-tile base (128-col GEMMs, 2 tiles)
    const int arow = mt*16 + (l & 15);
    const int drow = mt*16 + ((l >> 4) << 2);
    const int dcol = l & 15;

    // VALU phase geometry
    const int c  = t & 127;
    const int g  = t >> 7;
    const int cp = (t & 127)*2;
    const int si = t >> 4;
    const int sj = t & 15;

    // ---- P1 (MFMA dual): q1 = st@Wqp -> B1, k1 = st@Wkp -> B2 ----
    {
        f32x4v aq0={0.f,0.f,0.f,0.f}, aq1={0.f,0.f,0.f,0.f};
        f32x4v ak0={0.f,0.f,0.f,0.f}, ak1={0.f,0.f,0.f,0.f};
        const unsigned short* ab = Xoa + arow*168 + (l>>4)*8;
        #pragma unroll
        for (int kt = 0; kt < 4; kt++){
            bf16x8 a   = *reinterpret_cast<const bf16x8*>(ab + kt*32);
            bf16x8 bq0 = *reinterpret_cast<const bf16x8*>(Wqps + (size_t)((kt*8+ntb  )*64 + l)*8);
            bf16x8 bq1 = *reinterpret_cast<const bf16x8*>(Wqps + (size_t)((kt*8+ntb+1)*64 + l)*8);
            bf16x8 bk0 = *reinterpret_cast<const bf16x8*>(Wkps + (size_t)((kt*8+ntb  )*64 + l)*8);
            bf16x8 bk1 = *reinterpret_cast<const bf16x8*>(Wkps + (size_t)((kt*8+ntb+1)*64 + l)*8);
            aq0 = mfma16(a, bq0, aq0); aq1 = mfma16(a, bq1, aq1);
            ak0 = mfma16(a, bk0, ak0); ak1 = mfma16(a, bk1, ak1);
        }
        #pragma unroll
        for (int r = 0; r < 4; r++){
            B1[(drow+r)*132 + ntb*16     + dcol] = aq0[r];
            B1[(drow+r)*132 + (ntb+1)*16 + dcol] = aq1[r];
            B2[(drow+r)*132 + ntb*16     + dcol] = ak0[r];
            B2[(drow+r)*132 + (ntb+1)*16 + dcol] = ak1[r];
        }
    }
    __syncthreads();

    // ---- P2: w1 = softmax(q1@k1^T * scale) ----
    scores_softmax512(B1, B2, scale, Wb1f, out_w1 + (size_t)b*1024, si, sj);
    __syncthreads();

    // ---- P3 (VALU): u = w1@st -> Ubf (bf16, over B1) ----
    {
        float au[8];
        #pragma unroll
        for (int u=0;u<8;u++) au[u]=0.f;
        #pragma unroll
        for (int k0=0;k0<32;k0+=4){
            float4 xv[8];
            #pragma unroll
            for (int u=0;u<8;u++) xv[u] = ld4(Wb1f + (g*8+u)*36 + k0);
            #pragma unroll
            for (int kk=0;kk<4;kk++){
                float w = bf2f(Xoa[(k0+kk)*168 + c]);
                #pragma unroll
                for (int u=0;u<8;u++) au[u] = fmaf(elem(xv[u],kk), w, au[u]);
            }
        }
        __syncthreads();   // all scores/B1 traffic done before bf16 overwrite
        #pragma unroll
        for (int u=0;u<8;u++) Ubf[(g*8+u)*136 + c] = (unsigned short)f2bf(au[u]);
    }
    __syncthreads();

    // ---- P4 (MFMA): wav1 = u@Wvp -> Wvbf (bf16, over B2) ----
    {
        f32x4v av0={0.f,0.f,0.f,0.f}, av1={0.f,0.f,0.f,0.f};
        const unsigned short* ab = Ubf + arow*136 + (l>>4)*8;
        #pragma unroll
        for (int kt = 0; kt < 4; kt++){
            bf16x8 a  = *reinterpret_cast<const bf16x8*>(ab + kt*32);
            bf16x8 b0 = *reinterpret_cast<const bf16x8*>(Wvps + (size_t)((kt*8+ntb  )*64 + l)*8);
            bf16x8 b1 = *reinterpret_cast<const bf16x8*>(Wvps + (size_t)((kt*8+ntb+1)*64 + l)*8);
            av0 = mfma16(a, b0, av0); av1 = mfma16(a, b1, av1);
        }
        #pragma unroll
        for (int r = 0; r < 4; r++){
            Wvbf[(drow+r)*136 + ntb*16     + dcol] = (unsigned short)f2bf(av0[r]);
            Wvbf[(drow+r)*136 + (ntb+1)*16 + dcol] = (unsigned short)f2bf(av1[r]);
        }
    }
    __syncthreads();

    // ---- P5 (MFMA dual): q2 = wav1@Wq, k2 = wav1@Wk -> regs -> B1,B2 ----
    {
        f32x4v aq0={0.f,0.f,0.f,0.f}, aq1={0.f,0.f,0.f,0.f};
        f32x4v ak0={0.f,0.f,0.f,0.f}, ak1={0.f,0.f,0.f,0.f};
        const unsigned short* ab = Wvbf + arow*136 + (l>>4)*8;
        #pragma unroll
        for (int kt = 0; kt < 4; kt++){
            bf16x8 a   = *reinterpret_cast<const bf16x8*>(ab + kt*32);
            bf16x8 bq0 = *reinterpret_cast<const bf16x8*>(Wqs + (size_t)((kt*8+ntb  )*64 + l)*8);
            bf16x8 bq1 = *reinterpret_cast<const bf16x8*>(Wqs + (size_t)((kt*8+ntb+1)*64 + l)*8);
            bf16x8 bk0 = *reinterpret_cast<const bf16x8*>(Wks + (size_t)((kt*8+ntb  )*64 + l)*8);
            bf16x8 bk1 = *reinterpret_cast<const bf16x8*>(Wks + (size_t)((kt*8+ntb+1)*64 + l)*8);
            aq0 = mfma16(a, bq0, aq0); aq1 = mfma16(a, bq1, aq1);
            ak0 = mfma16(a, bk0, ak0); ak1 = mfma16(a, bk1, ak1);
        }
        __syncthreads();   // everyone done reading Wvbf
        #pragma unroll
        for (int r = 0; r < 4; r++){
            B1[(drow+r)*132 + ntb*16     + dcol] = aq0[r];
            B1[(drow+r)*132 + (ntb+1)*16 + dcol] = aq1[r];
            B2[(drow+r)*132 + ntb*16     + dcol] = ak0[r];
            B2[(drow+r)*132 + (ntb+1)*16 + dcol] = ak1[r];
        }
    }
    __syncthreads();

    // ---- P6: w2 = softmax(q2@k2^T * scale) ----
    scores_softmax512(B1, B2, scale, Wb2f, out_w2 + (size_t)b*1024, si, sj);
    __syncthreads();

    // ---- P7 (MFMA): A1 = [st|act|0]@WABswz (K=160, N=256) -> A1 fp32 ----
    {
        f32x4v ac[4];
        #pragma unroll
        for (int n=0;n<4;n++) ac[n] = f32x4v{0.f,0.f,0.f,0.f};
        const int nb7 = (wv >> 1) * 4;
        const unsigned short* ab = Xoa + arow*168 + (l>>4)*8;
        #pragma unroll
        for (int kt = 0; kt < 5; kt++){
            bf16x8 a = *reinterpret_cast<const bf16x8*>(ab + kt*32);
            #pragma unroll
            for (int n = 0; n < 4; n++){
                bf16x8 bb = *reinterpret_cast<const bf16x8*>(WABs + (size_t)((kt*16 + nb7 + n)*64 + l)*8);
                ac[n] = mfma16(a, bb, ac[n]);
            }
        }
        #pragma unroll
        for (int n = 0; n < 4; n++){
            #pragma unroll
            for (int r = 0; r < 4; r++)
                A1[(drow+r)*260 + (nb7+n)*16 + dcol] = ac[n][r];
        }
    }
    __syncthreads();

    // ---- P8 (VALU): P = w2@A1 (K=32) -> bf16 pack -> P2 (over dead Xoa) ----
    {
        float ap0[8], ap1[8];
        #pragma unroll
        for (int u=0;u<8;u++){ ap0[u]=0.f; ap1[u]=0.f; }
        #pragma unroll
        for (int k0=0;k0<32;k0+=4){
            float4 xv[8];
            #pragma unroll
            for (int u=0;u<8;u++) xv[u] = ld4(Wb2f + (g*8+u)*36 + k0);
            #pragma unroll
            for (int kk=0;kk<4;kk++){
                float2 w = *reinterpret_cast<const float2*>(A1 + (k0+kk)*260 + cp);
                #pragma unroll
                for (int u=0;u<8;u++){
                    float x = elem(xv[u],kk);
                    ap0[u] = fmaf(x, w.x, ap0[u]);
                    ap1[u] = fmaf(x, w.y, ap1[u]);
                }
            }
        }
        __syncthreads();  // A1/Xoa reads done before P2 overwrite
        #pragma unroll
        for (int u=0;u<8;u++)
            P2[(g*8+u)*128 + (cp>>1)] = pack2(ap0[u], ap1[u]);
    }
    __syncthreads();

    // ---- P9 (VALU): Q = (pol-act)@WB (K=16) -> bf16 pack -> Q2 (over dead A1) ----
    {
        float aq0[8], aq1[8];
        #pragma unroll
        for (int u=0;u<8;u++){ aq0[u]=0.f; aq1[u]=0.f; }
        const float* wB = WABf + 128*256;
        #pragma unroll
        for (int k0=0;k0<16;k0+=4){
            float4 xv[8];
            #pragma unroll
            for (int u=0;u<8;u++) xv[u] = ld4(APd + (g*8+u)*16 + k0);
            #pragma unroll
            for (int kk=0;kk<4;kk++){
                float2 w = *reinterpret_cast<const float2*>(wB + (k0+kk)*256 + cp);
                #pragma unroll
                for (int u=0;u<8;u++){
                    float x = elem(xv[u],kk);
                    aq0[u] = fmaf(x, w.x, aq0[u]);
                    aq1[u] = fmaf(x, w.y, aq1[u]);
                }
            }
        }
        #pragma unroll
        for (int u=0;u<8;u++)
            Q2[(g*8+u)*130 + (cp>>1)] = pack2(aq0[u], aq1[u]);
    }
    __syncthreads();

    // ---- P10: value[i,j] = sum_h W2[h] * leaky(P[i,h] + w2[i,j]*Q[j,h]) ----
    {
        float w00 = Wb2f[si*36 + sj], w01 = Wb2f[si*36 + sj + 16];
        float a0 = 0.f, a1 = 0.f;

        #define STEP(P_, Q_, W_, W2H, ACC) {                       \
            float t_ = fmaf((W_), (Q_), (P_));                     \
            float u_ = fmaf(0.495f, fabsf(t_), 0.505f * t_);       \
            (ACC) = fmaf(u_, (W2H), (ACC)); }

        #pragma unroll 8
        for (int hp=0; hp<128; hp++){
            unsigned pa = P2[si*128 + hp];
            unsigned qa = Q2[sj*130 + hp];
            unsigned qb = Q2[(sj+16)*130 + hp];
            float w2e = W2[2*hp], w2o = W2[2*hp+1];   // uniform -> scalar loads
            float paE = __uint_as_float(pa<<16), paO = __uint_as_float(pa & 0xffff0000u);
            float qaE = __uint_as_float(qa<<16), qaO = __uint_as_float(qa & 0xffff0000u);
            float qbE = __uint_as_float(qb<<16), qbO = __uint_as_float(qb & 0xffff0000u);
            STEP(paE, qaE, w00, w2e, a0)  STEP(paO, qaO, w00, w2o, a0)
            STEP(paE, qbE, w01, w2e, a1)  STEP(paO, qbO, w01, w2o, a1)
        }
        #undef STEP

        float* ov = out_v + (size_t)b*1024;
        ov[si*32 + sj]      = a0;
        ov[si*32 + sj + 16] = a1;
    }
}

extern "C" void kernel_launch(void* const* d_in, const int* in_sizes, int n_in,
                              void* d_out, int out_size, void* d_ws, size_t ws_size,
                              hipStream_t stream) {
    const float* states = (const float*)d_in[0];
    const float* pol    = (const float*)d_in[1];
    const float* act    = (const float*)d_in[2];
    const float* Wkp    = (const float*)d_in[3];
    const float* Wqp    = (const float*)d_in[4];
    const float* Wvp    = (const float*)d_in[5];
    const float* Wk     = (const float*)d_in[6];
    const float* Wq     = (const float*)d_in[7];
    const float* We     = (const float*)d_in[8];
    const float* Wav    = (const float*)d_in[9];
    const float* W1     = (const float*)d_in[10];
    const float* W2     = (const float*)d_in[11];

    float* out    = (float*)d_out;
    float* out_v  = out;                 // [256,32,32,1]
    float* out_w1 = out + 256*1024;      // [256,32,32]
    float* out_w2 = out + 2*256*1024;    // [256,32,32]

    // workspace layout (floats)
    float* WABf = (float*)d_ws;                                  // [144][256] fp32
    unsigned short* WABs = (unsigned short*)(WABf + 36864);      // 80 frags * 512 = 40960 ush
    unsigned short* wsu  = (unsigned short*)(WABf + 57344);
    unsigned short* Wqps = wsu;             // 32 frags * 512 = 16384 ush each
    unsigned short* Wkps = wsu + 16384;
    unsigned short* Wvps = wsu + 32768;
    unsigned short* Wqs  = wsu + 49152;
    unsigned short* Wks  = wsu + 65536;

    hipLaunchKernelGGL(k_pre, dim3(19), dim3(256), 0, stream,
                       We, Wav, W1, Wqp, Wkp, Wvp, Wq, Wk,
                       WABf, WABs, Wqps, Wkps, Wvps, Wqs, Wks);
    hipLaunchKernelGGL(k_main, dim3(NB), dim3(512), 0, stream,
                       states, pol, act,
                       Wqps, Wkps, Wvps, Wqs, Wks, WABs, WABf, W2,
                       out_v, out_w1, out_w2);
}

// Round 6
// 45.086 us; speedup vs baseline: 2.2752x; 1.3932x over previous
//
#include <hip/hip_runtime.h>
#include <math.h>

// Problem constants
#define NB 256   // batches
#define NN 32    // agents
#define DD 128   // state dim
#define NA 16    // action dim
#define HH 256   // hidden

using f32x4v  = __attribute__((ext_vector_type(4))) float;
using bf16x8  = __attribute__((ext_vector_type(8))) short;

static __device__ __forceinline__ float4 ld4(const float* p){ return *reinterpret_cast<const float4*>(p); }
static __device__ __forceinline__ void st4f(float* p, float4 v){ *reinterpret_cast<float4*>(p) = v; }
static __device__ __forceinline__ float elem(float4 v, int kk){
    return (kk==0)?v.x:(kk==1)?v.y:(kk==2)?v.z:v.w;
}

static __device__ __forceinline__ unsigned f2bf(float x){
    unsigned u = __float_as_uint(x);
    u += 0x7fffu + ((u >> 16) & 1u);   // round-to-nearest-even
    return u >> 16;
}
static __device__ __forceinline__ unsigned pack2(float a, float b){
    return f2bf(a) | (f2bf(b) << 16);
}
static __device__ __forceinline__ float bf2f(unsigned short s){
    return __uint_as_float(((unsigned)s) << 16);
}

static __device__ __forceinline__ f32x4v mfma16(bf16x8 a, bf16x8 b, f32x4v c){
    return __builtin_amdgcn_mfma_f32_16x16x32_bf16(a, b, c, 0, 0, 0);
}

// write one B-fragment (16 bf16 bytes per lane) to the swizzled weight buffer
static __device__ __forceinline__ void store_frag(unsigned short* __restrict__ dst,
                                                  int frag, int l, const float v[8]){
    uint4 p;
    p.x = pack2(v[0], v[1]); p.y = pack2(v[2], v[3]);
    p.z = pack2(v[4], v[5]); p.w = pack2(v[6], v[7]);
    *reinterpret_cast<uint4*>(dst + (size_t)(frag*64 + l)*8) = p;
}

// =============================================================================
// k_pre (restructured for parallelism): WAB = We @ (Wav @ W1), column tiles
// independent end-to-end.
//   blocks 0..15 : 16-col tile ct of WAB. T2tile = Wav@W1[:,16] then
//                  WABtile = We@T2tile (rows 144..159 zero); emit bf16 frags
//                  (kt=0..4, nt=ct) + fp32 rows 128..143 -> WABf.
//   blocks 16..25: fragment-swizzled bf16 copies of the 5 attention weights.
// Fragment layout (MFMA 16x16x32 B-frag): frag (kt,nt): lane l holds
//   B[kt*32+(l>>4)*8+i][nt*16+(l&15)], i=0..7.
// =============================================================================
__global__ __launch_bounds__(512)
void k_pre(const float* __restrict__ We, const float* __restrict__ Wav,
           const float* __restrict__ W1,
           const float* __restrict__ Wqp, const float* __restrict__ Wkp,
           const float* __restrict__ Wvp, const float* __restrict__ Wq,
           const float* __restrict__ Wk,
           float* __restrict__ WABf, unsigned short* __restrict__ WABs,
           unsigned short* __restrict__ Wqps, unsigned short* __restrict__ Wkps,
           unsigned short* __restrict__ Wvps, unsigned short* __restrict__ Wqs,
           unsigned short* __restrict__ Wks)
{
    __shared__ float W1c[128*16];    // W1 col-slice; reused as T2s after sync
    __shared__ float WABt[160*16];   // WAB col-tile fp32 (rows 144..159 zero)
    const int t = threadIdx.x;
    const int bid = blockIdx.x;

    if (bid < 16) {
        const int ct = bid;   // output col tile: cols ct*16 .. ct*16+15

        // stage W1[:, ct*16..+16) -> W1c[128][16]
        {
            int k = t >> 2, c4 = (t & 3) * 4;
            st4f(W1c + k*16 + c4, ld4(W1 + k*256 + ct*16 + c4));
        }
        __syncthreads();

        // GEMM1: T2[m][c] = sum_k Wav[m][k] * W1c[k][c]
        // thread: m = t>>2 (128 rows), cq = t&3 (4 cols)
        const int m = t >> 2, cq = t & 3;
        float a1[4] = {0.f,0.f,0.f,0.f};
        {
            const float* wrow = Wav + m*128;
            #pragma unroll 4
            for (int k0 = 0; k0 < 128; k0 += 4) {
                float4 xv = ld4(wrow + k0);
                #pragma unroll
                for (int kk = 0; kk < 4; kk++) {
                    float4 wr = ld4(W1c + (k0+kk)*16 + cq*4);
                    float x = elem(xv, kk);
                    a1[0] = fmaf(x, wr.x, a1[0]);
                    a1[1] = fmaf(x, wr.y, a1[1]);
                    a1[2] = fmaf(x, wr.z, a1[2]);
                    a1[3] = fmaf(x, wr.w, a1[3]);
                }
            }
        }
        __syncthreads();   // all W1c reads done
        st4f(W1c + m*16 + cq*4, make_float4(a1[0],a1[1],a1[2],a1[3]));  // W1c is now T2s
        __syncthreads();

        // GEMM2: WAB[r][c] = sum_k We[r][k] * T2s[k][c]
        // thread: rg = t>>4 (32 groups), c = t&15; rows r = rg + 32u, u<5
        const int rg = t >> 4, c = t & 15;
        const bool v4 = (rg < 16);   // row 128+rg valid (We has 144 rows)
        float a2[5] = {0.f,0.f,0.f,0.f,0.f};
        {
            #pragma unroll 2
            for (int k0 = 0; k0 < 128; k0 += 4) {
                float4 xv[5];
                #pragma unroll
                for (int u = 0; u < 4; u++) xv[u] = ld4(We + (rg + 32*u)*128 + k0);
                xv[4] = v4 ? ld4(We + (128 + rg)*128 + k0) : make_float4(0.f,0.f,0.f,0.f);
                #pragma unroll
                for (int kk = 0; kk < 4; kk++) {
                    float w = W1c[(k0+kk)*16 + c];
                    #pragma unroll
                    for (int u = 0; u < 5; u++)
                        a2[u] = fmaf(elem(xv[u],kk), w, a2[u]);
                }
            }
        }
        #pragma unroll
        for (int u = 0; u < 5; u++)
            WABt[(rg + 32*u)*16 + c] = a2[u];   // u=4 & rg>=16 writes 0 (zero pad)
        if (v4) WABf[(size_t)(128 + rg)*256 + ct*16 + c] = a2[4];
        __syncthreads();

        // swizzle-emit: 5 frags (kt=0..4, nt=ct)
        if (t < 320) {
            int kt = t >> 6, l = t & 63;
            float v[8];
            #pragma unroll
            for (int i = 0; i < 8; i++)
                v[i] = WABt[(kt*32 + (l>>4)*8 + i)*16 + (l&15)];
            store_frag(WABs, kt*16 + ct, l, v);
        }
    } else {
        // attention weights: sel = (bid-16)>>1, half = (bid-16)&1
        const int sel = (bid - 16) >> 1, half = (bid - 16) & 1;
        const float* W = (sel==0) ? Wqp : (sel==1) ? Wkp : (sel==2) ? Wvp :
                         (sel==3) ? Wq : Wk;
        unsigned short* dst = (sel==0) ? Wqps : (sel==1) ? Wkps : (sel==2) ? Wvps :
                              (sel==3) ? Wqs : Wks;
        #pragma unroll
        for (int ss = 0; ss < 2; ss++){
            int s = half*1024 + t + 512*ss;
            int frag = s >> 6, l = s & 63;
            int kt = frag >> 3, nt = frag & 7;
            float v[8];
            #pragma unroll
            for (int i=0;i<8;i++)
                v[i] = W[(kt*32 + (l>>4)*8 + i)*128 + nt*16 + (l&15)];
            store_frag(dst, frag, l, v);
        }
    }
}

// scores+softmax, 512 threads: thread (i=t>>4, j=t&15) covers (i,j) and (i,j+16).
static __device__ __forceinline__ void scores_softmax512(const float* __restrict__ Qm,
                                                         const float* __restrict__ Km,
                                                         float scale,
                                                         float* __restrict__ w_lds,
                                                         float* __restrict__ w_out,
                                                         int i, int j)
{
    float s0 = 0.f, s1 = 0.f;
    #pragma unroll 4
    for (int k=0;k<128;k+=4){
        float4 qv = ld4(Qm + i*132 + k);
        float4 k0 = ld4(Km + j*132 + k);
        float4 k1 = ld4(Km + (j+16)*132 + k);
        s0 += qv.x*k0.x + qv.y*k0.y + qv.z*k0.z + qv.w*k0.w;
        s1 += qv.x*k1.x + qv.y*k1.y + qv.z*k1.z + qv.w*k1.w;
    }
    s0 *= scale; s1 *= scale;
    float m = fmaxf(s0, s1);
    #pragma unroll
    for (int d=1; d<16; d<<=1) m = fmaxf(m, __shfl_xor(m, d));
    float e0 = expf(s0 - m), e1 = expf(s1 - m);
    float sum = e0 + e1;
    #pragma unroll
    for (int d=1; d<16; d<<=1) sum += __shfl_xor(sum, d);
    float inv = 1.f / sum;
    e0 *= inv; e1 *= inv;
    w_lds[i*36 + j]      = e0;
    w_lds[i*36 + j + 16] = e1;
    w_out[i*32 + j]      = e0;
    w_out[i*32 + j + 16] = e1;
}

// =============================================================================
// k_main: one block per batch, 512 threads (8 waves). Heavy GEMMs on MFMA.
// =============================================================================
__global__ __launch_bounds__(512)
void k_main(const float* __restrict__ states, const float* __restrict__ pol,
            const float* __restrict__ act,
            const unsigned short* __restrict__ Wqps, const unsigned short* __restrict__ Wkps,
            const unsigned short* __restrict__ Wvps, const unsigned short* __restrict__ Wqs,
            const unsigned short* __restrict__ Wks,  const unsigned short* __restrict__ WABs,
            const float* __restrict__ WABf, const float* __restrict__ W2,
            float* __restrict__ out_v, float* __restrict__ out_w1,
            float* __restrict__ out_w2)
{
    const int b = blockIdx.x;
    const int t = threadIdx.x;
    const float scale = 0.08838834764831845f;  // 1/sqrt(128)

    __shared__ float SH[16000];   // 62.5 KB
    float* B1   = SH;                                   // 32x132
    float* B2   = SH + 4224;                            // 32x132
    float* Wb2f = SH + 8448;                            // 32x36
    float* Wb1f = SH + 9600;                            // 32x36
    float* APd  = SH + 10752;                           // 32x16 (pol-act)
    unsigned short* Xoa  = (unsigned short*)(SH + 11264); // [32][168] bf16 (st|act|0)
    unsigned short* Ubf  = (unsigned short*)B1;           // [32][136] bf16
    unsigned short* Wvbf = (unsigned short*)B2;           // [32][136] bf16
    float*    A1 = SH;                                   // [32][260] fp32 (over B1+B2)
    unsigned* P2 = (unsigned*)(SH + 11904);              // [32][128] packed bf16 (over dead Xoa)
    unsigned* Q2 = (unsigned*)SH;                        // [32][130] packed bf16 (over dead A1)

    const float* stg  = states + (size_t)b*(NN*DD);
    const float* actg = act + (size_t)b*(NN*NA);
    const float* polg = pol + (size_t)b*(NN*NA);

    // ---- stage Xoa = bf16([st | act | 0]) (k 0..159), APd = pol-act ----
    {
        int r = t >> 4, kb = t & 15;
        #pragma unroll
        for (int uu = 0; uu < 10; uu++){
            int k = kb + 16*uu;
            float v = (k < 128) ? stg[r*128 + k]
                    : (k < 144) ? actg[r*16 + (k-128)] : 0.f;
            Xoa[r*168 + k] = (unsigned short)f2bf(v);
        }
        if (t < 128) {
            int rr = t>>2, cc = (t&3)*4;
            float4 p = ld4(polg + rr*16 + cc), a = ld4(actg + rr*16 + cc);
            st4f(APd + rr*16 + cc, make_float4(p.x-a.x, p.y-a.y, p.z-a.z, p.w-a.w));
        }
    }
    __syncthreads();

    // MFMA wave geometry
    const int l    = t & 63;
    const int wv   = t >> 6;             // wave 0..7
    const int mt   = wv & 1;             // M-tile
    const int ntb  = (wv >> 1) * 2;      // N-tile base (128-col GEMMs, 2 tiles)
    const int arow = mt*16 + (l & 15);
    const int drow = mt*16 + ((l >> 4) << 2);
    const int dcol = l & 15;

    // VALU phase geometry
    const int c  = t & 127;
    const int g  = t >> 7;
    const int cp = (t & 127)*2;
    const int si = t >> 4;
    const int sj = t & 15;

    // ---- P1 (MFMA dual): q1 = st@Wqp -> B1, k1 = st@Wkp -> B2 ----
    {
        f32x4v aq0={0.f,0.f,0.f,0.f}, aq1={0.f,0.f,0.f,0.f};
        f32x4v ak0={0.f,0.f,0.f,0.f}, ak1={0.f,0.f,0.f,0.f};
        const unsigned short* ab = Xoa + arow*168 + (l>>4)*8;
        #pragma unroll
        for (int kt = 0; kt < 4; kt++){
            bf16x8 a   = *reinterpret_cast<const bf16x8*>(ab + kt*32);
            bf16x8 bq0 = *reinterpret_cast<const bf16x8*>(Wqps + (size_t)((kt*8+ntb  )*64 + l)*8);
            bf16x8 bq1 = *reinterpret_cast<const bf16x8*>(Wqps + (size_t)((kt*8+ntb+1)*64 + l)*8);
            bf16x8 bk0 = *reinterpret_cast<const bf16x8*>(Wkps + (size_t)((kt*8+ntb  )*64 + l)*8);
            bf16x8 bk1 = *reinterpret_cast<const bf16x8*>(Wkps + (size_t)((kt*8+ntb+1)*64 + l)*8);
            aq0 = mfma16(a, bq0, aq0); aq1 = mfma16(a, bq1, aq1);
            ak0 = mfma16(a, bk0, ak0); ak1 = mfma16(a, bk1, ak1);
        }
        #pragma unroll
        for (int r = 0; r < 4; r++){
            B1[(drow+r)*132 + ntb*16     + dcol] = aq0[r];
            B1[(drow+r)*132 + (ntb+1)*16 + dcol] = aq1[r];
            B2[(drow+r)*132 + ntb*16     + dcol] = ak0[r];
            B2[(drow+r)*132 + (ntb+1)*16 + dcol] = ak1[r];
        }
    }
    __syncthreads();

    // ---- P2: w1 = softmax(q1@k1^T * scale) ----
    scores_softmax512(B1, B2, scale, Wb1f, out_w1 + (size_t)b*1024, si, sj);
    __syncthreads();

    // ---- P3 (VALU): u = w1@st -> Ubf (bf16, over B1) ----
    {
        float au[8];
        #pragma unroll
        for (int u=0;u<8;u++) au[u]=0.f;
        #pragma unroll
        for (int k0=0;k0<32;k0+=4){
            float4 xv[8];
            #pragma unroll
            for (int u=0;u<8;u++) xv[u] = ld4(Wb1f + (g*8+u)*36 + k0);
            #pragma unroll
            for (int kk=0;kk<4;kk++){
                float w = bf2f(Xoa[(k0+kk)*168 + c]);
                #pragma unroll
                for (int u=0;u<8;u++) au[u] = fmaf(elem(xv[u],kk), w, au[u]);
            }
        }
        __syncthreads();   // all scores/B1 traffic done before bf16 overwrite
        #pragma unroll
        for (int u=0;u<8;u++) Ubf[(g*8+u)*136 + c] = (unsigned short)f2bf(au[u]);
    }
    __syncthreads();

    // ---- P4 (MFMA): wav1 = u@Wvp -> Wvbf (bf16, over B2) ----
    {
        f32x4v av0={0.f,0.f,0.f,0.f}, av1={0.f,0.f,0.f,0.f};
        const unsigned short* ab = Ubf + arow*136 + (l>>4)*8;
        #pragma unroll
        for (int kt = 0; kt < 4; kt++){
            bf16x8 a  = *reinterpret_cast<const bf16x8*>(ab + kt*32);
            bf16x8 b0 = *reinterpret_cast<const bf16x8*>(Wvps + (size_t)((kt*8+ntb  )*64 + l)*8);
            bf16x8 b1 = *reinterpret_cast<const bf16x8*>(Wvps + (size_t)((kt*8+ntb+1)*64 + l)*8);
            av0 = mfma16(a, b0, av0); av1 = mfma16(a, b1, av1);
        }
        #pragma unroll
        for (int r = 0; r < 4; r++){
            Wvbf[(drow+r)*136 + ntb*16     + dcol] = (unsigned short)f2bf(av0[r]);
            Wvbf[(drow+r)*136 + (ntb+1)*16 + dcol] = (unsigned short)f2bf(av1[r]);
        }
    }
    __syncthreads();

    // ---- P5 (MFMA dual): q2 = wav1@Wq, k2 = wav1@Wk -> regs -> B1,B2 ----
    {
        f32x4v aq0={0.f,0.f,0.f,0.f}, aq1={0.f,0.f,0.f,0.f};
        f32x4v ak0={0.f,0.f,0.f,0.f}, ak1={0.f,0.f,0.f,0.f};
        const unsigned short* ab = Wvbf + arow*136 + (l>>4)*8;
        #pragma unroll
        for (int kt = 0; kt < 4; kt++){
            bf16x8 a   = *reinterpret_cast<const bf16x8*>(ab + kt*32);
            bf16x8 bq0 = *reinterpret_cast<const bf16x8*>(Wqs + (size_t)((kt*8+ntb  )*64 + l)*8);
            bf16x8 bq1 = *reinterpret_cast<const bf16x8*>(Wqs + (size_t)((kt*8+ntb+1)*64 + l)*8);
            bf16x8 bk0 = *reinterpret_cast<const bf16x8*>(Wks + (size_t)((kt*8+ntb  )*64 + l)*8);
            bf16x8 bk1 = *reinterpret_cast<const bf16x8*>(Wks + (size_t)((kt*8+ntb+1)*64 + l)*8);
            aq0 = mfma16(a, bq0, aq0); aq1 = mfma16(a, bq1, aq1);
            ak0 = mfma16(a, bk0, ak0); ak1 = mfma16(a, bk1, ak1);
        }
        __syncthreads();   // everyone done reading Wvbf
        #pragma unroll
        for (int r = 0; r < 4; r++){
            B1[(drow+r)*132 + ntb*16     + dcol] = aq0[r];
            B1[(drow+r)*132 + (ntb+1)*16 + dcol] = aq1[r];
            B2[(drow+r)*132 + ntb*16     + dcol] = ak0[r];
            B2[(drow+r)*132 + (ntb+1)*16 + dcol] = ak1[r];
        }
    }
    __syncthreads();

    // ---- P6: w2 = softmax(q2@k2^T * scale) ----
    scores_softmax512(B1, B2, scale, Wb2f, out_w2 + (size_t)b*1024, si, sj);
    __syncthreads();

    // ---- P7 (MFMA): A1 = [st|act|0]@WABswz (K=160, N=256) -> A1 fp32 ----
    {
        f32x4v ac[4];
        #pragma unroll
        for (int n=0;n<4;n++) ac[n] = f32x4v{0.f,0.f,0.f,0.f};
        const int nb7 = (wv >> 1) * 4;
        const unsigned short* ab = Xoa + arow*168 + (l>>4)*8;
        #pragma unroll
        for (int kt = 0; kt < 5; kt++){
            bf16x8 a = *reinterpret_cast<const bf16x8*>(ab + kt*32);
            #pragma unroll
            for (int n = 0; n < 4; n++){
                bf16x8 bb = *reinterpret_cast<const bf16x8*>(WABs + (size_t)((kt*16 + nb7 + n)*64 + l)*8);
                ac[n] = mfma16(a, bb, ac[n]);
            }
        }
        #pragma unroll
        for (int n = 0; n < 4; n++){
            #pragma unroll
            for (int r = 0; r < 4; r++)
                A1[(drow+r)*260 + (nb7+n)*16 + dcol] = ac[n][r];
        }
    }
    __syncthreads();

    // ---- P8 (VALU): P = w2@A1 (K=32) -> bf16 pack -> P2 (over dead Xoa) ----
    {
        float ap0[8], ap1[8];
        #pragma unroll
        for (int u=0;u<8;u++){ ap0[u]=0.f; ap1[u]=0.f; }
        #pragma unroll
        for (int k0=0;k0<32;k0+=4){
            float4 xv[8];
            #pragma unroll
            for (int u=0;u<8;u++) xv[u] = ld4(Wb2f + (g*8+u)*36 + k0);
            #pragma unroll
            for (int kk=0;kk<4;kk++){
                float2 w = *reinterpret_cast<const float2*>(A1 + (k0+kk)*260 + cp);
                #pragma unroll
                for (int u=0;u<8;u++){
                    float x = elem(xv[u],kk);
                    ap0[u] = fmaf(x, w.x, ap0[u]);
                    ap1[u] = fmaf(x, w.y, ap1[u]);
                }
            }
        }
        __syncthreads();  // A1/Xoa reads done before P2 overwrite
        #pragma unroll
        for (int u=0;u<8;u++)
            P2[(g*8+u)*128 + (cp>>1)] = pack2(ap0[u], ap1[u]);
    }
    __syncthreads();

    // ---- P9 (VALU): Q = (pol-act)@WB (K=16) -> bf16 pack -> Q2 (over dead A1) ----
    {
        float aq0[8], aq1[8];
        #pragma unroll
        for (int u=0;u<8;u++){ aq0[u]=0.f; aq1[u]=0.f; }
        const float* wB = WABf + 128*256;
        #pragma unroll
        for (int k0=0;k0<16;k0+=4){
            float4 xv[8];
            #pragma unroll
            for (int u=0;u<8;u++) xv[u] = ld4(APd + (g*8+u)*16 + k0);
            #pragma unroll
            for (int kk=0;kk<4;kk++){
                float2 w = *reinterpret_cast<const float2*>(wB + (k0+kk)*256 + cp);
                #pragma unroll
                for (int u=0;u<8;u++){
                    float x = elem(xv[u],kk);
                    aq0[u] = fmaf(x, w.x, aq0[u]);
                    aq1[u] = fmaf(x, w.y, aq1[u]);
                }
            }
        }
        #pragma unroll
        for (int u=0;u<8;u++)
            Q2[(g*8+u)*130 + (cp>>1)] = pack2(aq0[u], aq1[u]);
    }
    __syncthreads();

    // ---- P10: value[i,j] = sum_h W2[h] * leaky(P[i,h] + w2[i,j]*Q[j,h]) ----
    {
        float w00 = Wb2f[si*36 + sj], w01 = Wb2f[si*36 + sj + 16];
        float a0 = 0.f, a1 = 0.f;

        #define STEP(P_, Q_, W_, W2H, ACC) {                       \
            float t_ = fmaf((W_), (Q_), (P_));                     \
            float u_ = fmaf(0.495f, fabsf(t_), 0.505f * t_);       \
            (ACC) = fmaf(u_, (W2H), (ACC)); }

        #pragma unroll 8
        for (int hp=0; hp<128; hp++){
            unsigned pa = P2[si*128 + hp];
            unsigned qa = Q2[sj*130 + hp];
            unsigned qb = Q2[(sj+16)*130 + hp];
            float w2e = W2[2*hp], w2o = W2[2*hp+1];   // uniform -> scalar loads
            float paE = __uint_as_float(pa<<16), paO = __uint_as_float(pa & 0xffff0000u);
            float qaE = __uint_as_float(qa<<16), qaO = __uint_as_float(qa & 0xffff0000u);
            float qbE = __uint_as_float(qb<<16), qbO = __uint_as_float(qb & 0xffff0000u);
            STEP(paE, qaE, w00, w2e, a0)  STEP(paO, qaO, w00, w2o, a0)
            STEP(paE, qbE, w01, w2e, a1)  STEP(paO, qbO, w01, w2o, a1)
        }
        #undef STEP

        float* ov = out_v + (size_t)b*1024;
        ov[si*32 + sj]      = a0;
        ov[si*32 + sj + 16] = a1;
    }
}

extern "C" void kernel_launch(void* const* d_in, const int* in_sizes, int n_in,
                              void* d_out, int out_size, void* d_ws, size_t ws_size,
                              hipStream_t stream) {
    const float* states = (const float*)d_in[0];
    const float* pol    = (const float*)d_in[1];
    const float* act    = (const float*)d_in[2];
    const float* Wkp    = (const float*)d_in[3];
    const float* Wqp    = (const float*)d_in[4];
    const float* Wvp    = (const float*)d_in[5];
    const float* Wk     = (const float*)d_in[6];
    const float* Wq     = (const float*)d_in[7];
    const float* We     = (const float*)d_in[8];
    const float* Wav    = (const float*)d_in[9];
    const float* W1     = (const float*)d_in[10];
    const float* W2     = (const float*)d_in[11];

    float* out    = (float*)d_out;
    float* out_v  = out;                 // [256,32,32,1]
    float* out_w1 = out + 256*1024;      // [256,32,32]
    float* out_w2 = out + 2*256*1024;    // [256,32,32]

    // workspace layout (floats)
    float* WABf = (float*)d_ws;                                  // [144][256] fp32 (rows 128..143 used)
    unsigned short* WABs = (unsigned short*)(WABf + 36864);      // 80 frags * 512 = 40960 ush
    unsigned short* wsu  = (unsigned short*)(WABf + 57344);
    unsigned short* Wqps = wsu;             // 32 frags * 512 = 16384 ush each
    unsigned short* Wkps = wsu + 16384;
    unsigned short* Wvps = wsu + 32768;
    unsigned short* Wqs  = wsu + 49152;
    unsigned short* Wks  = wsu + 65536;

    hipLaunchKernelGGL(k_pre, dim3(26), dim3(512), 0, stream,
                       We, Wav, W1, Wqp, Wkp, Wvp, Wq, Wk,
                       WABf, WABs, Wqps, Wkps, Wvps, Wqs, Wks);
    hipLaunchKernelGGL(k_main, dim3(NB), dim3(512), 0, stream,
                       states, pol, act,
                       Wqps, Wkps, Wvps, Wqs, Wks, WABs, WABf, W2,
                       out_v, out_w1, out_w2);
}

// Round 7
// 44.965 us; speedup vs baseline: 2.2813x; 1.0027x over previous
//
#include <hip/hip_runtime.h>
#include <math.h>

// Problem constants
#define NB 256   // batches
#define NN 32    // agents
#define DD 128   // state dim
#define NA 16    // action dim
#define HH 256   // hidden

using f32x4v  = __attribute__((ext_vector_type(4))) float;
using bf16x8  = __attribute__((ext_vector_type(8))) short;

static __device__ __forceinline__ float4 ld4(const float* p){ return *reinterpret_cast<const float4*>(p); }
static __device__ __forceinline__ void st4f(float* p, float4 v){ *reinterpret_cast<float4*>(p) = v; }
static __device__ __forceinline__ float elem(float4 v, int kk){
    return (kk==0)?v.x:(kk==1)?v.y:(kk==2)?v.z:v.w;
}

static __device__ __forceinline__ unsigned f2bf(float x){
    unsigned u = __float_as_uint(x);
    u += 0x7fffu + ((u >> 16) & 1u);   // round-to-nearest-even
    return u >> 16;
}
static __device__ __forceinline__ unsigned pack2(float a, float b){
    return f2bf(a) | (f2bf(b) << 16);
}
static __device__ __forceinline__ float bf2f(unsigned short s){
    return __uint_as_float(((unsigned)s) << 16);
}

static __device__ __forceinline__ f32x4v mfma16(bf16x8 a, bf16x8 b, f32x4v c){
    return __builtin_amdgcn_mfma_f32_16x16x32_bf16(a, b, c, 0, 0, 0);
}

// write one B-fragment (16 bf16 bytes per lane) to the swizzled weight buffer
static __device__ __forceinline__ void store_frag(unsigned short* __restrict__ dst,
                                                  int frag, int l, const float v[8]){
    uint4 p;
    p.x = pack2(v[0], v[1]); p.y = pack2(v[2], v[3]);
    p.z = pack2(v[4], v[5]); p.w = pack2(v[6], v[7]);
    *reinterpret_cast<uint4*>(dst + (size_t)(frag*64 + l)*8) = p;
}

// =============================================================================
// k_pre (1024 threads): WAB = We @ (Wav @ W1), independent 16-col tiles.
//   blocks 0..15 : col tile ct. T2 = Wav@W1[:,16]; WABtile = We@T2 (rows
//                  144..159 zero); emit bf16 frags (kt 0..4, nt=ct) + fp32
//                  rows 128..143 -> WABf.
//   blocks 16..25: fragment-swizzled bf16 copies of 5 attention weights.
// Fragment layout (16x16x32 B-frag): frag (kt,nt): lane l holds
//   B[kt*32+(l>>4)*8+i][nt*16+(l&15)], i=0..7.
// =============================================================================
__global__ __launch_bounds__(1024)
void k_pre(const float* __restrict__ We, const float* __restrict__ Wav,
           const float* __restrict__ W1,
           const float* __restrict__ Wqp, const float* __restrict__ Wkp,
           const float* __restrict__ Wvp, const float* __restrict__ Wq,
           const float* __restrict__ Wk,
           float* __restrict__ WABf, unsigned short* __restrict__ WABs,
           unsigned short* __restrict__ Wqps, unsigned short* __restrict__ Wkps,
           unsigned short* __restrict__ Wvps, unsigned short* __restrict__ Wqs,
           unsigned short* __restrict__ Wks)
{
    __shared__ float W1c[128*16];    // W1 col-slice; becomes T2 after sync
    __shared__ float WABt[160*16];   // WAB col-tile fp32 (rows 144..159 zero)
    const int t = threadIdx.x;
    const int bid = blockIdx.x;

    if (bid < 16) {
        const int ct = bid;

        // stage W1[:, ct*16..+16): 1024 float2
        {
            int k = t >> 3, c2 = (t & 7) * 2;
            *reinterpret_cast<float2*>(W1c + k*16 + c2) =
                *reinterpret_cast<const float2*>(W1 + k*256 + ct*16 + c2);
        }
        __syncthreads();

        // GEMM1: T2[m][c] = sum_k Wav[m][k]*W1c[k][c]; thread: m=t>>3, 2 cols
        const int m = t >> 3, cq2 = (t & 7) * 2;
        float a1x = 0.f, a1y = 0.f;
        {
            const float* wrow = Wav + m*128;
            #pragma unroll 4
            for (int k0 = 0; k0 < 128; k0 += 4) {
                float4 xv = ld4(wrow + k0);
                #pragma unroll
                for (int kk = 0; kk < 4; kk++) {
                    float2 wr = *reinterpret_cast<const float2*>(W1c + (k0+kk)*16 + cq2);
                    float x = elem(xv, kk);
                    a1x = fmaf(x, wr.x, a1x);
                    a1y = fmaf(x, wr.y, a1y);
                }
            }
        }
        __syncthreads();   // all W1c reads done
        W1c[m*16 + cq2]     = a1x;
        W1c[m*16 + cq2 + 1] = a1y;   // W1c is now T2
        __syncthreads();

        // GEMM2: WAB[r][c] = sum_k We[r][k]*T2[k][c]
        // thread: rg = t>>4 (0..63), c = t&15; rows rg, rg+64, 128+rg (rg<32)
        const int rg = t >> 4, c = t & 15;
        float a20 = 0.f, a21 = 0.f, a22 = 0.f;
        {
            #pragma unroll 2
            for (int k0 = 0; k0 < 128; k0 += 4) {
                float4 xv0 = ld4(We + rg*128 + k0);
                float4 xv1 = ld4(We + (rg+64)*128 + k0);
                float4 xv2 = (rg < 16) ? ld4(We + (128+rg)*128 + k0)
                                       : make_float4(0.f,0.f,0.f,0.f);
                #pragma unroll
                for (int kk = 0; kk < 4; kk++) {
                    float w = W1c[(k0+kk)*16 + c];
                    a20 = fmaf(elem(xv0,kk), w, a20);
                    a21 = fmaf(elem(xv1,kk), w, a21);
                    a22 = fmaf(elem(xv2,kk), w, a22);
                }
            }
        }
        WABt[rg*16 + c]      = a20;
        WABt[(rg+64)*16 + c] = a21;
        if (rg < 32) WABt[(128+rg)*16 + c] = a22;    // rg>=16 contributes zeros
        if (rg < 16) WABf[(size_t)(128 + rg)*256 + ct*16 + c] = a22;
        __syncthreads();

        // swizzle-emit: 5 frags (kt=0..4, nt=ct)
        if (t < 320) {
            int kt = t >> 6, l = t & 63;
            float v[8];
            #pragma unroll
            for (int i = 0; i < 8; i++)
                v[i] = WABt[(kt*32 + (l>>4)*8 + i)*16 + (l&15)];
            store_frag(WABs, kt*16 + ct, l, v);
        }
    } else {
        // attention weights: sel = (bid-16)>>1, half = (bid-16)&1; 1 slot/thread
        const int sel = (bid - 16) >> 1, half = (bid - 16) & 1;
        const float* W = (sel==0) ? Wqp : (sel==1) ? Wkp : (sel==2) ? Wvp :
                         (sel==3) ? Wq : Wk;
        unsigned short* dst = (sel==0) ? Wqps : (sel==1) ? Wkps : (sel==2) ? Wvps :
                              (sel==3) ? Wqs : Wks;
        int s = half*1024 + t;
        int frag = s >> 6, l = s & 63;
        int kt = frag >> 3, nt = frag & 7;
        float v[8];
        #pragma unroll
        for (int i=0;i<8;i++)
            v[i] = W[(kt*32 + (l>>4)*8 + i)*128 + nt*16 + (l&15)];
        store_frag(dst, frag, l, v);
    }
}

// scores+softmax, 512 threads: thread (i=t>>4, j=t&15) covers (i,j) and (i,j+16).
static __device__ __forceinline__ void scores_softmax512(const float* __restrict__ Qm,
                                                         const float* __restrict__ Km,
                                                         float scale,
                                                         float* __restrict__ w_lds,
                                                         float* __restrict__ w_out,
                                                         int i, int j)
{
    float s0 = 0.f, s1 = 0.f;
    #pragma unroll 4
    for (int k=0;k<128;k+=4){
        float4 qv = ld4(Qm + i*132 + k);
        float4 k0 = ld4(Km + j*132 + k);
        float4 k1 = ld4(Km + (j+16)*132 + k);
        s0 += qv.x*k0.x + qv.y*k0.y + qv.z*k0.z + qv.w*k0.w;
        s1 += qv.x*k1.x + qv.y*k1.y + qv.z*k1.z + qv.w*k1.w;
    }
    s0 *= scale; s1 *= scale;
    float m = fmaxf(s0, s1);
    #pragma unroll
    for (int d=1; d<16; d<<=1) m = fmaxf(m, __shfl_xor(m, d));
    float e0 = expf(s0 - m), e1 = expf(s1 - m);
    float sum = e0 + e1;
    #pragma unroll
    for (int d=1; d<16; d<<=1) sum += __shfl_xor(sum, d);
    float inv = 1.f / sum;
    e0 *= inv; e1 *= inv;
    w_lds[i*36 + j]      = e0;
    w_lds[i*36 + j + 16] = e1;
    w_out[i*32 + j]      = e0;
    w_out[i*32 + j + 16] = e1;
}

// =============================================================================
// k_main: one block per batch, 512 threads (8 waves).
// Critical path: stage -> P1 -> sm1 -> P3 -> P4 -> P5 -> sm2 -> A1store ->
// P8 -> Q2store -> P10.  A1 (MFMA) hoisted next to P1; Q (VALU) hoisted to
// right after staging; both register-resident until their store slots.
// =============================================================================
__global__ __launch_bounds__(512)
void k_main(const float* __restrict__ states, const float* __restrict__ pol,
            const float* __restrict__ act,
            const unsigned short* __restrict__ Wqps, const unsigned short* __restrict__ Wkps,
            const unsigned short* __restrict__ Wvps, const unsigned short* __restrict__ Wqs,
            const unsigned short* __restrict__ Wks,  const unsigned short* __restrict__ WABs,
            const float* __restrict__ WABf, const float* __restrict__ W2,
            float* __restrict__ out_v, float* __restrict__ out_w1,
            float* __restrict__ out_w2)
{
    const int b = blockIdx.x;
    const int t = threadIdx.x;
    const float scale = 0.08838834764831845f;  // 1/sqrt(128)

    __shared__ float SH[16000];   // 62.5 KB
    float* B1   = SH;                                   // 32x132
    float* B2   = SH + 4224;                            // 32x132
    float* Wb2f = SH + 8448;                            // 32x36
    float* Wb1f = SH + 9600;                            // 32x36
    float* APd  = SH + 10752;                           // 32x16 (pol-act)
    unsigned short* Xoa  = (unsigned short*)(SH + 11264); // [32][168] bf16 (st|act|0)
    unsigned short* Ubf  = (unsigned short*)B1;           // [32][136] bf16
    unsigned short* Wvbf = (unsigned short*)B2;           // [32][136] bf16
    float*    A1 = SH;                                   // [32][260] fp32 (over B1+B2)
    unsigned* P2 = (unsigned*)(SH + 11904);              // [32][128] packed bf16 (over dead Xoa)
    unsigned* Q2 = (unsigned*)SH;                        // [32][132] packed bf16 (over dead A1)
    float* SPQ = Wb1f;   // SP[32][2] at 0, SQ[32][2] at +64 (Wb1f dead after P3)

    const float* stg  = states + (size_t)b*(NN*DD);
    const float* actg = act + (size_t)b*(NN*NA);
    const float* polg = pol + (size_t)b*(NN*NA);

    // ---- stage Xoa = bf16([st | act | 0]) (k 0..159), APd = pol-act ----
    {
        int r = t >> 4, kb = t & 15;
        #pragma unroll
        for (int uu = 0; uu < 10; uu++){
            int k = kb + 16*uu;
            float v = (k < 128) ? stg[r*128 + k]
                    : (k < 144) ? actg[r*16 + (k-128)] : 0.f;
            Xoa[r*168 + k] = (unsigned short)f2bf(v);
        }
        if (t < 128) {
            int rr = t>>2, cc = (t&3)*4;
            float4 p = ld4(polg + rr*16 + cc), a = ld4(actg + rr*16 + cc);
            st4f(APd + rr*16 + cc, make_float4(p.x-a.x, p.y-a.y, p.z-a.z, p.w-a.w));
        }
    }
    __syncthreads();

    // MFMA wave geometry
    const int l    = t & 63;
    const int wv   = t >> 6;             // wave 0..7
    const int mt   = wv & 1;             // M-tile
    const int ntb  = (wv >> 1) * 2;      // N-tile base (128-col GEMMs)
    const int nb7  = (wv >> 1) * 4;      // N-tile base (256-col GEMM)
    const int arow = mt*16 + (l & 15);
    const int drow = mt*16 + ((l >> 4) << 2);
    const int dcol = l & 15;

    // VALU phase geometry
    const int c  = t & 127;
    const int g  = t >> 7;
    const int cp = (t & 127)*2;
    const int si = t >> 4;
    const int sj = t & 15;
    const int wp = wv & 1;

    // ---- Q-hoist (VALU): Q = (pol-act)@WB (K=16) -> regs + SQ butterfly ----
    float qr0[8], qr1[8], sq[8];
    {
        #pragma unroll
        for (int u=0;u<8;u++){ qr0[u]=0.f; qr1[u]=0.f; }
        const float* wB = WABf + 128*256;
        #pragma unroll
        for (int k0=0;k0<16;k0+=4){
            float4 xv[8];
            #pragma unroll
            for (int u=0;u<8;u++) xv[u] = ld4(APd + (g*8+u)*16 + k0);
            #pragma unroll
            for (int kk=0;kk<4;kk++){
                float2 w = *reinterpret_cast<const float2*>(wB + (k0+kk)*256 + cp);
                #pragma unroll
                for (int u=0;u<8;u++){
                    float x = elem(xv[u],kk);
                    qr0[u] = fmaf(x, w.x, qr0[u]);
                    qr1[u] = fmaf(x, w.y, qr1[u]);
                }
            }
        }
        float2 w2v = *reinterpret_cast<const float2*>(W2 + cp);
        #pragma unroll
        for (int u=0;u<8;u++) sq[u] = qr0[u]*w2v.x + qr1[u]*w2v.y;
        #pragma unroll
        for (int d=1; d<64; d<<=1){
            #pragma unroll
            for (int u=0;u<8;u++) sq[u] += __shfl_xor(sq[u], d);
        }
    }

    // ---- P1 (MFMA dual): q1 = st@Wqp -> B1, k1 = st@Wkp -> B2 ----
    {
        f32x4v aq0={0.f,0.f,0.f,0.f}, aq1={0.f,0.f,0.f,0.f};
        f32x4v ak0={0.f,0.f,0.f,0.f}, ak1={0.f,0.f,0.f,0.f};
        const unsigned short* ab = Xoa + arow*168 + (l>>4)*8;
        #pragma unroll
        for (int kt = 0; kt < 4; kt++){
            bf16x8 a   = *reinterpret_cast<const bf16x8*>(ab + kt*32);
            bf16x8 bq0 = *reinterpret_cast<const bf16x8*>(Wqps + (size_t)((kt*8+ntb  )*64 + l)*8);
            bf16x8 bq1 = *reinterpret_cast<const bf16x8*>(Wqps + (size_t)((kt*8+ntb+1)*64 + l)*8);
            bf16x8 bk0 = *reinterpret_cast<const bf16x8*>(Wkps + (size_t)((kt*8+ntb  )*64 + l)*8);
            bf16x8 bk1 = *reinterpret_cast<const bf16x8*>(Wkps + (size_t)((kt*8+ntb+1)*64 + l)*8);
            aq0 = mfma16(a, bq0, aq0); aq1 = mfma16(a, bq1, aq1);
            ak0 = mfma16(a, bk0, ak0); ak1 = mfma16(a, bk1, ak1);
        }
        #pragma unroll
        for (int r = 0; r < 4; r++){
            B1[(drow+r)*132 + ntb*16     + dcol] = aq0[r];
            B1[(drow+r)*132 + (ntb+1)*16 + dcol] = aq1[r];
            B2[(drow+r)*132 + ntb*16     + dcol] = ak0[r];
            B2[(drow+r)*132 + (ntb+1)*16 + dcol] = ak1[r];
        }
    }

    // ---- A1-hoist (MFMA): ac = [st|act|0]@WAB (K=160), regs until post-sm2 ----
    f32x4v ac[4];
    {
        #pragma unroll
        for (int n=0;n<4;n++) ac[n] = f32x4v{0.f,0.f,0.f,0.f};
        const unsigned short* ab = Xoa + arow*168 + (l>>4)*8;
        #pragma unroll
        for (int kt = 0; kt < 5; kt++){
            bf16x8 a = *reinterpret_cast<const bf16x8*>(ab + kt*32);
            #pragma unroll
            for (int n = 0; n < 4; n++){
                bf16x8 bb = *reinterpret_cast<const bf16x8*>(WABs + (size_t)((kt*16 + nb7 + n)*64 + l)*8);
                ac[n] = mfma16(a, bb, ac[n]);
            }
        }
    }
    __syncthreads();

    // ---- P2: w1 = softmax(q1@k1^T * scale) ----
    scores_softmax512(B1, B2, scale, Wb1f, out_w1 + (size_t)b*1024, si, sj);
    __syncthreads();

    // ---- P3 (VALU): u = w1@st -> Ubf (bf16, over B1) ----
    {
        float au[8];
        #pragma unroll
        for (int u=0;u<8;u++) au[u]=0.f;
        #pragma unroll
        for (int k0=0;k0<32;k0+=4){
            float4 xv[8];
            #pragma unroll
            for (int u=0;u<8;u++) xv[u] = ld4(Wb1f + (g*8+u)*36 + k0);
            #pragma unroll
            for (int kk=0;kk<4;kk++){
                float w = bf2f(Xoa[(k0+kk)*168 + c]);
                #pragma unroll
                for (int u=0;u<8;u++) au[u] = fmaf(elem(xv[u],kk), w, au[u]);
            }
        }
        #pragma unroll
        for (int u=0;u<8;u++) Ubf[(g*8+u)*136 + c] = (unsigned short)f2bf(au[u]);
    }
    __syncthreads();

    // ---- P4 (MFMA): wav1 = u@Wvp -> Wvbf (bf16, over B2) ----
    {
        f32x4v av0={0.f,0.f,0.f,0.f}, av1={0.f,0.f,0.f,0.f};
        const unsigned short* ab = Ubf + arow*136 + (l>>4)*8;
        #pragma unroll
        for (int kt = 0; kt < 4; kt++){
            bf16x8 a  = *reinterpret_cast<const bf16x8*>(ab + kt*32);
            bf16x8 b0 = *reinterpret_cast<const bf16x8*>(Wvps + (size_t)((kt*8+ntb  )*64 + l)*8);
            bf16x8 b1 = *reinterpret_cast<const bf16x8*>(Wvps + (size_t)((kt*8+ntb+1)*64 + l)*8);
            av0 = mfma16(a, b0, av0); av1 = mfma16(a, b1, av1);
        }
        #pragma unroll
        for (int r = 0; r < 4; r++){
            Wvbf[(drow+r)*136 + ntb*16     + dcol] = (unsigned short)f2bf(av0[r]);
            Wvbf[(drow+r)*136 + (ntb+1)*16 + dcol] = (unsigned short)f2bf(av1[r]);
        }
    }
    __syncthreads();

    // ---- P5 (MFMA dual): q2 = wav1@Wq, k2 = wav1@Wk -> regs -> B1,B2 ----
    {
        f32x4v aq0={0.f,0.f,0.f,0.f}, aq1={0.f,0.f,0.f,0.f};
        f32x4v ak0={0.f,0.f,0.f,0.f}, ak1={0.f,0.f,0.f,0.f};
        const unsigned short* ab = Wvbf + arow*136 + (l>>4)*8;
        #pragma unroll
        for (int kt = 0; kt < 4; kt++){
            bf16x8 a   = *reinterpret_cast<const bf16x8*>(ab + kt*32);
            bf16x8 bq0 = *reinterpret_cast<const bf16x8*>(Wqs + (size_t)((kt*8+ntb  )*64 + l)*8);
            bf16x8 bq1 = *reinterpret_cast<const bf16x8*>(Wqs + (size_t)((kt*8+ntb+1)*64 + l)*8);
            bf16x8 bk0 = *reinterpret_cast<const bf16x8*>(Wks + (size_t)((kt*8+ntb  )*64 + l)*8);
            bf16x8 bk1 = *reinterpret_cast<const bf16x8*>(Wks + (size_t)((kt*8+ntb+1)*64 + l)*8);
            aq0 = mfma16(a, bq0, aq0); aq1 = mfma16(a, bq1, aq1);
            ak0 = mfma16(a, bk0, ak0); ak1 = mfma16(a, bk1, ak1);
        }
        __syncthreads();   // everyone done reading Wvbf
        #pragma unroll
        for (int r = 0; r < 4; r++){
            B1[(drow+r)*132 + ntb*16     + dcol] = aq0[r];
            B1[(drow+r)*132 + (ntb+1)*16 + dcol] = aq1[r];
            B2[(drow+r)*132 + ntb*16     + dcol] = ak0[r];
            B2[(drow+r)*132 + (ntb+1)*16 + dcol] = ak1[r];
        }
    }
    __syncthreads();

    // ---- P6: w2 = softmax(q2@k2^T * scale) ----
    scores_softmax512(B1, B2, scale, Wb2f, out_w2 + (size_t)b*1024, si, sj);
    __syncthreads();

    // ---- A1 store (over dead B1/B2) ----
    {
        #pragma unroll
        for (int n = 0; n < 4; n++){
            #pragma unroll
            for (int r = 0; r < 4; r++)
                A1[(drow+r)*260 + (nb7+n)*16 + dcol] = ac[n][r];
        }
    }
    __syncthreads();

    // ---- P8 (VALU): P = w2@A1 (K=32) -> bf16 P2 (over dead Xoa) + SP ----
    {
        float ap0[8], ap1[8];
        #pragma unroll
        for (int u=0;u<8;u++){ ap0[u]=0.f; ap1[u]=0.f; }
        #pragma unroll
        for (int k0=0;k0<32;k0+=4){
            float4 xv[8];
            #pragma unroll
            for (int u=0;u<8;u++) xv[u] = ld4(Wb2f + (g*8+u)*36 + k0);
            #pragma unroll
            for (int kk=0;kk<4;kk++){
                float2 w = *reinterpret_cast<const float2*>(A1 + (k0+kk)*260 + cp);
                #pragma unroll
                for (int u=0;u<8;u++){
                    float x = elem(xv[u],kk);
                    ap0[u] = fmaf(x, w.x, ap0[u]);
                    ap1[u] = fmaf(x, w.y, ap1[u]);
                }
            }
        }
        #pragma unroll
        for (int u=0;u<8;u++)
            P2[(g*8+u)*128 + (cp>>1)] = pack2(ap0[u], ap1[u]);
        // SP[row] = sum_h W2[h]*P[row][h]: per-lane partial + wave butterfly
        float2 w2v = *reinterpret_cast<const float2*>(W2 + cp);
        float sp[8];
        #pragma unroll
        for (int u=0;u<8;u++) sp[u] = ap0[u]*w2v.x + ap1[u]*w2v.y;
        #pragma unroll
        for (int d=1; d<64; d<<=1){
            #pragma unroll
            for (int u=0;u<8;u++) sp[u] += __shfl_xor(sp[u], d);
        }
        if (l == 0){
            #pragma unroll
            for (int u=0;u<8;u++) SPQ[(g*8+u)*2 + wp] = sp[u];
        }
    }
    __syncthreads();

    // ---- Q2 store (over dead A1) + SQ partials ----
    {
        #pragma unroll
        for (int u=0;u<8;u++)
            Q2[(g*8+u)*132 + (cp>>1)] = pack2(qr0[u], qr1[u]);
        if (l == 0){
            #pragma unroll
            for (int u=0;u<8;u++) SPQ[64 + (g*8+u)*2 + wp] = sq[u];
        }
    }
    __syncthreads();

    // ---- P10: value[i,j] = 0.505*(SP[i]+w*SQ[j]) + 0.495*sum_h W2[h]*|..| ----
    {
        float w00 = Wb2f[si*36 + sj], w01 = Wb2f[si*36 + sj + 16];
        float SPi = SPQ[si*2] + SPQ[si*2+1];
        float SQa = SPQ[64 + sj*2] + SPQ[64 + sj*2+1];
        float SQb = SPQ[64 + (sj+16)*2] + SPQ[64 + (sj+16)*2+1];
        float a0 = 0.f, a1 = 0.f;

        #define PROC(PA,QA,QB,H2) {                                         \
            float w2e = W2[(H2)], w2o = W2[(H2)+1];                         \
            float paE = __uint_as_float((PA)<<16), paO = __uint_as_float((PA) & 0xffff0000u); \
            float qaE = __uint_as_float((QA)<<16), qaO = __uint_as_float((QA) & 0xffff0000u); \
            float qbE = __uint_as_float((QB)<<16), qbO = __uint_as_float((QB) & 0xffff0000u); \
            float t0 = fmaf(w00, qaE, paE); a0 = fmaf(fabsf(t0), w2e, a0);  \
            float t1 = fmaf(w00, qaO, paO); a0 = fmaf(fabsf(t1), w2o, a0);  \
            float t2 = fmaf(w01, qbE, paE); a1 = fmaf(fabsf(t2), w2e, a1);  \
            float t3 = fmaf(w01, qbO, paO); a1 = fmaf(fabsf(t3), w2o, a1); }

        #pragma unroll 4
        for (int hp4 = 0; hp4 < 32; hp4++){
            uint4 pa4 = *reinterpret_cast<const uint4*>(P2 + si*128 + hp4*4);
            uint4 qa4 = *reinterpret_cast<const uint4*>(Q2 + sj*132 + hp4*4);
            uint4 qb4 = *reinterpret_cast<const uint4*>(Q2 + (sj+16)*132 + hp4*4);
            PROC(pa4.x, qa4.x, qb4.x, hp4*8+0)
            PROC(pa4.y, qa4.y, qb4.y, hp4*8+2)
            PROC(pa4.z, qa4.z, qb4.z, hp4*8+4)
            PROC(pa4.w, qa4.w, qb4.w, hp4*8+6)
        }
        #undef PROC

        float* ov = out_v + (size_t)b*1024;
        ov[si*32 + sj]      = fmaf(0.495f, a0, 0.505f*(SPi + w00*SQa));
        ov[si*32 + sj + 16] = fmaf(0.495f, a1, 0.505f*(SPi + w01*SQb));
    }
}

extern "C" void kernel_launch(void* const* d_in, const int* in_sizes, int n_in,
                              void* d_out, int out_size, void* d_ws, size_t ws_size,
                              hipStream_t stream) {
    const float* states = (const float*)d_in[0];
    const float* pol    = (const float*)d_in[1];
    const float* act    = (const float*)d_in[2];
    const float* Wkp    = (const float*)d_in[3];
    const float* Wqp    = (const float*)d_in[4];
    const float* Wvp    = (const float*)d_in[5];
    const float* Wk     = (const float*)d_in[6];
    const float* Wq     = (const float*)d_in[7];
    const float* We     = (const float*)d_in[8];
    const float* Wav    = (const float*)d_in[9];
    const float* W1     = (const float*)d_in[10];
    const float* W2     = (const float*)d_in[11];

    float* out    = (float*)d_out;
    float* out_v  = out;                 // [256,32,32,1]
    float* out_w1 = out + 256*1024;      // [256,32,32]
    float* out_w2 = out + 2*256*1024;    // [256,32,32]

    // workspace layout (floats)
    float* WABf = (float*)d_ws;                                  // [144][256] fp32 (rows 128..143 used)
    unsigned short* WABs = (unsigned short*)(WABf + 36864);      // 80 frags * 512 = 40960 ush
    unsigned short* wsu  = (unsigned short*)(WABf + 57344);
    unsigned short* Wqps = wsu;             // 32 frags * 512 = 16384 ush each
    unsigned short* Wkps = wsu + 16384;
    unsigned short* Wvps = wsu + 32768;
    unsigned short* Wqs  = wsu + 49152;
    unsigned short* Wks  = wsu + 65536;

    hipLaunchKernelGGL(k_pre, dim3(26), dim3(1024), 0, stream,
                       We, Wav, W1, Wqp, Wkp, Wvp, Wq, Wk,
                       WABf, WABs, Wqps, Wkps, Wvps, Wqs, Wks);
    hipLaunchKernelGGL(k_main, dim3(NB), dim3(512), 0, stream,
                       states, pol, act,
                       Wqps, Wkps, Wvps, Wqs, Wks, WABs, WABf, W2,
                       out_v, out_w1, out_w2);
}